// Round 11
// baseline (391.910 us; speedup 1.0000x reference)
//
#include <hip/hip_runtime.h>
#include <hip/hip_bf16.h>
#include <math.h>

#define NN   100000
#define EE   1600000
#define ETOT (NN + EE)
#define IND  128
#define HD   128    // HEADS*HID
#define OD   40
#define NEG  0.2f
#define BNEPS 1e-5f
#define NBKT 16     // BN-stat buckets

typedef __attribute__((ext_vector_type(8))) short bf16x8;
typedef __attribute__((ext_vector_type(4))) float f32x4;

__device__ __forceinline__ float lrelu(float x) { return x > 0.f ? x : NEG * x; }

__device__ __forceinline__ unsigned pack_bf16(float a, float b) {
  unsigned ua = __float_as_uint(a), ub = __float_as_uint(b);
  ua = (ua + 0x7fffu + ((ua >> 16) & 1u)) >> 16;
  ub = (ub + 0x7fffu + ((ub >> 16) & 1u)) >> 16;
  return ua | (ub << 16);
}
__device__ __forceinline__ float bf16_lo(unsigned v) { return __uint_as_float(v << 16); }
__device__ __forceinline__ float bf16_hi(unsigned v) { return __uint_as_float(v & 0xffff0000u); }

// ---- prep: W0 transpose-pack (first 8192 threads) + degrank 4 edges/thread ----
__global__ void prep_kernel(const float* __restrict__ W0, unsigned* __restrict__ w0t,
                            const int* __restrict__ ei, int* __restrict__ deg,
                            int* __restrict__ rank) {
  int gid = blockIdx.x * blockDim.x + threadIdx.x;
  if (gid < 128 * 64) {
    int n = gid & 127, kp = gid >> 7;
    float lo = W0[(size_t)(2 * kp) * 128 + n];
    float hi = W0[(size_t)(2 * kp + 1) * 128 + n];
    w0t[n * 64 + kp] = pack_bf16(lo, hi);
  }
  int i4 = gid * 4;
  if (i4 >= ETOT) return;
  int4 d;
  if (i4 < EE) d = *(const int4*)&ei[EE + i4];
  else         d = make_int4(i4 - EE, i4 - EE + 1, i4 - EE + 2, i4 - EE + 3);
  int4 r;
  r.x = atomicAdd(&deg[d.x], 1);
  r.y = atomicAdd(&deg[d.y], 1);
  r.z = atomicAdd(&deg[d.z], 1);
  r.w = atomicAdd(&deg[d.w], 1);
  *(int4*)&rank[i4] = r;
}

// ---- GEMM0 via MFMA + fused alpha logits ----
__global__ __launch_bounds__(256) void gemm0_kernel(const float* __restrict__ x,
                                                    const unsigned* __restrict__ w0t,
                                                    const float* __restrict__ a_src0,
                                                    const float* __restrict__ a_dst0,
                                                    unsigned* __restrict__ h0b,
                                                    float* __restrict__ asrc0,
                                                    float* __restrict__ adst0) {
  __shared__ __align__(16) unsigned As[64][68];   // bf16x2 [row][k/2]
  __shared__ __align__(16) unsigned Wt[128][68];  // bf16x2 [col][k/2]
  int t = threadIdx.x;
  int rowbase = blockIdx.x * 64;
  for (int idx = t; idx < 128 * 64; idx += 256) {
    Wt[idx >> 6][idx & 63] = w0t[idx];
  }
  for (int idx = t; idx < 64 * 64; idx += 256) {
    int row = idx >> 6, kp = idx & 63;
    int r = rowbase + row;
    int rc = r < NN ? r : NN - 1;
    float2 v = *(const float2*)&x[(size_t)rc * 128 + kp * 2];
    As[row][kp] = pack_bf16(v.x, v.y);
  }
  __syncthreads();

  int lane = t & 63, w = t >> 6;
  int mrow = lane & 15, g = lane >> 4;
  f32x4 acc[8];
#pragma unroll
  for (int nt = 0; nt < 8; nt++) acc[nt] = (f32x4){0.f, 0.f, 0.f, 0.f};
#pragma unroll
  for (int ks = 0; ks < 4; ks++) {
    bf16x8 a = *(const bf16x8*)&As[w * 16 + mrow][ks * 16 + g * 4];
#pragma unroll
    for (int nt = 0; nt < 8; nt++) {
      bf16x8 b = *(const bf16x8*)&Wt[nt * 16 + mrow][ks * 16 + g * 4];
      acc[nt] = __builtin_amdgcn_mfma_f32_16x16x32_bf16(a, b, acc[nt], 0, 0, 0);
    }
  }
  int col = lane & 15;
  float as_[8], ad_[8];
#pragma unroll
  for (int nt = 0; nt < 8; nt++) {
    as_[nt] = a_src0[nt * 16 + col];
    ad_[nt] = a_dst0[nt * 16 + col];
  }
#pragma unroll
  for (int reg = 0; reg < 4; reg++) {
    int r = rowbase + w * 16 + g * 4 + reg;
    bool rok = r < NN;
    float hs0 = acc[0][reg] * as_[0] + acc[1][reg] * as_[1];
    float hs1 = acc[2][reg] * as_[2] + acc[3][reg] * as_[3];
    float hs2 = acc[4][reg] * as_[4] + acc[5][reg] * as_[5];
    float hs3 = acc[6][reg] * as_[6] + acc[7][reg] * as_[7];
    float hd0 = acc[0][reg] * ad_[0] + acc[1][reg] * ad_[1];
    float hd1 = acc[2][reg] * ad_[2] + acc[3][reg] * ad_[3];
    float hd2 = acc[4][reg] * ad_[4] + acc[5][reg] * ad_[5];
    float hd3 = acc[6][reg] * ad_[6] + acc[7][reg] * ad_[7];
#pragma unroll
    for (int mk = 1; mk < 16; mk <<= 1) {
      hs0 += __shfl_xor(hs0, mk); hs1 += __shfl_xor(hs1, mk);
      hs2 += __shfl_xor(hs2, mk); hs3 += __shfl_xor(hs3, mk);
      hd0 += __shfl_xor(hd0, mk); hd1 += __shfl_xor(hd1, mk);
      hd2 += __shfl_xor(hd2, mk); hd3 += __shfl_xor(hd3, mk);
    }
    if ((lane & 15) == 0 && rok) {
      asrc0[r * 4 + 0] = hs0; asrc0[r * 4 + 1] = hs1;
      asrc0[r * 4 + 2] = hs2; asrc0[r * 4 + 3] = hs3;
      adst0[r * 4 + 0] = hd0; adst0[r * 4 + 1] = hd1;
      adst0[r * 4 + 2] = hd2; adst0[r * 4 + 3] = hd3;
    }
#pragma unroll
    for (int nt = 0; nt < 8; nt++) {
      float v = acc[nt][reg];
      float nv = __shfl_xor(v, 1);
      if (!(col & 1) && rok) h0b[(size_t)r * 64 + nt * 8 + (col >> 1)] = pack_bf16(v, nv);
    }
  }
}

// ---------------- CSR scans ----------------
__global__ __launch_bounds__(256) void scanA_kernel(const int* __restrict__ deg,
                                                    int* __restrict__ scanned,
                                                    int* __restrict__ blocksums) {
  __shared__ int s[256];
  int t = threadIdx.x;
  int i = blockIdx.x * 256 + t;
  int v = (i < NN) ? deg[i] : 0;
  s[t] = v;
  __syncthreads();
  for (int off = 1; off < 256; off <<= 1) {
    int add = (t >= off) ? s[t - off] : 0;
    __syncthreads();
    s[t] += add;
    __syncthreads();
  }
  if (i < NN) scanned[i] = s[t];
  if (t == 255) blocksums[blockIdx.x] = s[255];
}

__global__ __launch_bounds__(512) void scanB_kernel(int* __restrict__ blocksums, int NB) {
  __shared__ int s[512];
  int t = threadIdx.x;
  int v = (t < NB) ? blocksums[t] : 0;
  s[t] = v;
  __syncthreads();
  for (int off = 1; off < 512; off <<= 1) {
    int add = (t >= off) ? s[t - off] : 0;
    __syncthreads();
    s[t] += add;
    __syncthreads();
  }
  if (t < NB) blocksums[t] = s[t] - v;  // exclusive block offset
}

__global__ __launch_bounds__(256) void scanC_kernel(const int* __restrict__ scanned,
                                                    const int* __restrict__ deg,
                                                    const int* __restrict__ blocksums,
                                                    int* __restrict__ rowptr) {
  int i = blockIdx.x * 256 + threadIdx.x;
  if (i < NN) rowptr[i] = blocksums[blockIdx.x] + scanned[i] - deg[i];
  if (i == 0) rowptr[NN] = ETOT;
}

// 4 edges/thread scatter
__global__ void scatter_kernel(const int* __restrict__ ei, const int* __restrict__ rowptr,
                               const int* __restrict__ rank, int* __restrict__ csr_src) {
  int i4 = (blockIdx.x * blockDim.x + threadIdx.x) * 4;
  if (i4 >= ETOT) return;
  int4 s, d;
  if (i4 < EE) {
    s = *(const int4*)&ei[i4];
    d = *(const int4*)&ei[EE + i4];
  } else {
    s = make_int4(i4 - EE, i4 - EE + 1, i4 - EE + 2, i4 - EE + 3);
    d = s;
  }
  int4 rk = *(const int4*)&rank[i4];
  int p0 = rowptr[d.x] + rk.x;
  int p1 = rowptr[d.y] + rk.y;
  int p2 = rowptr[d.z] + rk.z;
  int p3 = rowptr[d.w] + rk.w;
  csr_src[p0] = s.x;
  csr_src[p1] = s.y;
  csr_src[p2] = s.z;
  csr_src[p3] = s.w;
}

// ---- layer-0 aggregate, ONE HEAD per dispatch: working set 6.4 MB -> L2-friendly ----
// 16 lanes/node = 4 edge-quads x 4 chan-quads; uint4 loads (4 lanes x 16B = one 64B line).
// NN % 16 == 0 -> exactly 6250 full blocks.
__global__ __launch_bounds__(256) void agg0h_kernel(const int* __restrict__ csr_src,
                                                    const int* __restrict__ rowptr,
                                                    const float* __restrict__ asrc0,
                                                    const float* __restrict__ adst0,
                                                    const unsigned* __restrict__ h0b,
                                                    const float* __restrict__ b0,
                                                    unsigned* __restrict__ agg0b,
                                                    float* __restrict__ bnsumB,
                                                    float* __restrict__ bnsqB,
                                                    int head) {
  __shared__ float ws[16][17];
  __shared__ int   ss[16][16];
  __shared__ float Lsum[4][4][8], Lsq[4][4][8];
  int t = threadIdx.x;
  int grp = t >> 4, sub = t & 15;
  int edge_q = sub >> 2, chan_q = sub & 3;
  int n = blockIdx.x * 16 + grp;
  int start = rowptr[n], end = rowptr[n + 1];
  float ad = adst0[(size_t)n * 4 + head];
  int hoff = head * 16 + chan_q * 4;   // u32 offset of this lane's 16B within a row
  float a0 = 0.f, a1 = 0.f, a2 = 0.f, a3 = 0.f, a4 = 0.f, a5 = 0.f, a6 = 0.f, a7 = 0.f;
  float d = 0.f;

  for (int base = start; base < end; base += 16) {
    int cnt = min(16, end - base);
    if (sub < cnt) {
      int s = csr_src[base + sub];
      float w = __expf(lrelu(asrc0[(size_t)s * 4 + head] + ad));
      d += w;
      ss[grp][sub] = s;
      ws[grp][sub] = w;
    }
    __builtin_amdgcn_wave_barrier();
    for (int eb = 0; eb < cnt; eb += 4) {
      int e = eb + edge_q;
      bool v = e < cnt;
      float w = v ? ws[grp][e] : 0.f;
      int s = ss[grp][v ? e : 0];
      uint4 hv = *(const uint4*)&h0b[(size_t)s * 64 + hoff];
      a0 += w * bf16_lo(hv.x); a1 += w * bf16_hi(hv.x);
      a2 += w * bf16_lo(hv.y); a3 += w * bf16_hi(hv.y);
      a4 += w * bf16_lo(hv.z); a5 += w * bf16_hi(hv.z);
      a6 += w * bf16_lo(hv.w); a7 += w * bf16_hi(hv.w);
    }
    __builtin_amdgcn_wave_barrier();
  }
  // denominator: butterfly over the 16-lane group
#pragma unroll
  for (int mk = 1; mk < 16; mk <<= 1) d += __shfl_xor(d, mk);
  // channel accumulators: butterfly across edge_q (strides 4, 8) - hazard-free
  a0 += __shfl_xor(a0, 4); a1 += __shfl_xor(a1, 4);
  a2 += __shfl_xor(a2, 4); a3 += __shfl_xor(a3, 4);
  a4 += __shfl_xor(a4, 4); a5 += __shfl_xor(a5, 4);
  a6 += __shfl_xor(a6, 4); a7 += __shfl_xor(a7, 4);
  a0 += __shfl_xor(a0, 8); a1 += __shfl_xor(a1, 8);
  a2 += __shfl_xor(a2, 8); a3 += __shfl_xor(a3, 8);
  a4 += __shfl_xor(a4, 8); a5 += __shfl_xor(a5, 8);
  a6 += __shfl_xor(a6, 8); a7 += __shfl_xor(a7, 8);
  float rd = 1.f / d;
  int c = head * 32 + chan_q * 8;
  float4 bA = *(const float4*)&b0[c];
  float4 bB = *(const float4*)&b0[c + 4];
  float o0 = a0 * rd + bA.x, o1 = a1 * rd + bA.y;
  float o2 = a2 * rd + bA.z, o3 = a3 * rd + bA.w;
  float o4 = a4 * rd + bB.x, o5 = a5 * rd + bB.y;
  float o6 = a6 * rd + bB.z, o7 = a7 * rd + bB.w;
  if (sub < 4) {   // edge_q == 0 lanes write this node's 64B head chunk
    uint4 o;
    o.x = pack_bf16(o0, o1);
    o.y = pack_bf16(o2, o3);
    o.z = pack_bf16(o4, o5);
    o.w = pack_bf16(o6, o7);
    *(uint4*)&agg0b[(size_t)n * 64 + hoff] = o;
  }
  // fused BN stats for channels head*32 .. head*32+31
  float s0 = o0, s1 = o1, s2 = o2, s3 = o3, s4 = o4, s5 = o5, s6 = o6, s7 = o7;
  float q0 = o0 * o0, q1 = o1 * o1, q2 = o2 * o2, q3 = o3 * o3;
  float q4 = o4 * o4, q5 = o5 * o5, q6 = o6 * o6, q7 = o7 * o7;
#pragma unroll
  for (int mk = 16; mk < 64; mk <<= 1) {   // sum the wave's 4 nodes (same sub position)
    s0 += __shfl_xor(s0, mk); s1 += __shfl_xor(s1, mk);
    s2 += __shfl_xor(s2, mk); s3 += __shfl_xor(s3, mk);
    s4 += __shfl_xor(s4, mk); s5 += __shfl_xor(s5, mk);
    s6 += __shfl_xor(s6, mk); s7 += __shfl_xor(s7, mk);
    q0 += __shfl_xor(q0, mk); q1 += __shfl_xor(q1, mk);
    q2 += __shfl_xor(q2, mk); q3 += __shfl_xor(q3, mk);
    q4 += __shfl_xor(q4, mk); q5 += __shfl_xor(q5, mk);
    q6 += __shfl_xor(q6, mk); q7 += __shfl_xor(q7, mk);
  }
  int lane = t & 63, wv = t >> 6;
  if (lane < 4) {   // grp0-of-wave, edge_q==0: chan_q = lane
    Lsum[wv][lane][0] = s0; Lsum[wv][lane][1] = s1;
    Lsum[wv][lane][2] = s2; Lsum[wv][lane][3] = s3;
    Lsum[wv][lane][4] = s4; Lsum[wv][lane][5] = s5;
    Lsum[wv][lane][6] = s6; Lsum[wv][lane][7] = s7;
    Lsq[wv][lane][0] = q0; Lsq[wv][lane][1] = q1;
    Lsq[wv][lane][2] = q2; Lsq[wv][lane][3] = q3;
    Lsq[wv][lane][4] = q4; Lsq[wv][lane][5] = q5;
    Lsq[wv][lane][6] = q6; Lsq[wv][lane][7] = q7;
  }
  __syncthreads();
  if (t < 32) {   // channel = head*32 + t
    int cq = t >> 3, j = t & 7;
    float s = Lsum[0][cq][j] + Lsum[1][cq][j] + Lsum[2][cq][j] + Lsum[3][cq][j];
    float q = Lsq[0][cq][j] + Lsq[1][cq][j] + Lsq[2][cq][j] + Lsq[3][cq][j];
    int bkt = blockIdx.x & (NBKT - 1);
    atomicAdd(&bnsumB[bkt * 128 + head * 32 + t], s);
    atomicAdd(&bnsqB[bkt * 128 + head * 32 + t], q);
  }
}

// ---- GEMM1 via MFMA: BN finalize in prologue, fused BN+ELU, alpha1, bf16 h1 ----
__global__ __launch_bounds__(256) void gemm1_kernel(const unsigned* __restrict__ agg0b,
                                                    const float* __restrict__ bnsumB,
                                                    const float* __restrict__ bnsqB,
                                                    const float* __restrict__ gamma,
                                                    const float* __restrict__ beta,
                                                    const float* __restrict__ W1,
                                                    const float* __restrict__ a_src1,
                                                    const float* __restrict__ a_dst1,
                                                    unsigned* __restrict__ h1b,
                                                    float* __restrict__ asrc1,
                                                    float* __restrict__ adst1) {
  __shared__ __align__(16) unsigned As[64][68];
  __shared__ __align__(16) unsigned Wt[48][68];
  __shared__ float bnsc[128], bnsh[128];
  int t = threadIdx.x;
  int rowbase = blockIdx.x * 64;

  if (t < 128) {
    float s = 0.f, q = 0.f;
#pragma unroll
    for (int k = 0; k < NBKT; k++) {
      s += bnsumB[k * 128 + t];
      q += bnsqB[k * 128 + t];
    }
    float mu = s / (float)NN;
    float var = q / (float)NN - mu * mu;
    float sc = gamma[t] / sqrtf(var + BNEPS);
    bnsc[t] = sc;
    bnsh[t] = beta[t] - mu * sc;
  }
  for (int idx = t; idx < 48 * 64; idx += 256) {
    int c = idx >> 6, kp = idx & 63;
    float lo = (c < OD) ? W1[(size_t)(2 * kp) * OD + c] : 0.f;
    float hi = (c < OD) ? W1[(size_t)(2 * kp + 1) * OD + c] : 0.f;
    Wt[c][kp] = pack_bf16(lo, hi);
  }
  __syncthreads();
  for (int idx = t; idx < 64 * 16; idx += 256) {
    int row = idx >> 4, c4 = idx & 15;
    int r = rowbase + row;
    int rc = r < NN ? r : NN - 1;
    int k = c4 * 8;
    uint4 hv = *(const uint4*)&agg0b[(size_t)rc * 64 + c4 * 4];
    float y0 = bf16_lo(hv.x) * bnsc[k + 0] + bnsh[k + 0];
    float y1 = bf16_hi(hv.x) * bnsc[k + 1] + bnsh[k + 1];
    float y2 = bf16_lo(hv.y) * bnsc[k + 2] + bnsh[k + 2];
    float y3 = bf16_hi(hv.y) * bnsc[k + 3] + bnsh[k + 3];
    float y4 = bf16_lo(hv.z) * bnsc[k + 4] + bnsh[k + 4];
    float y5 = bf16_hi(hv.z) * bnsc[k + 5] + bnsh[k + 5];
    float y6 = bf16_lo(hv.w) * bnsc[k + 6] + bnsh[k + 6];
    float y7 = bf16_hi(hv.w) * bnsc[k + 7] + bnsh[k + 7];
    y0 = y0 > 0.f ? y0 : expm1f(y0);
    y1 = y1 > 0.f ? y1 : expm1f(y1);
    y2 = y2 > 0.f ? y2 : expm1f(y2);
    y3 = y3 > 0.f ? y3 : expm1f(y3);
    y4 = y4 > 0.f ? y4 : expm1f(y4);
    y5 = y5 > 0.f ? y5 : expm1f(y5);
    y6 = y6 > 0.f ? y6 : expm1f(y6);
    y7 = y7 > 0.f ? y7 : expm1f(y7);
    As[row][c4 * 4 + 0] = pack_bf16(y0, y1);
    As[row][c4 * 4 + 1] = pack_bf16(y2, y3);
    As[row][c4 * 4 + 2] = pack_bf16(y4, y5);
    As[row][c4 * 4 + 3] = pack_bf16(y6, y7);
  }
  __syncthreads();

  int lane = t & 63, w = t >> 6;
  int mrow = lane & 15, g = lane >> 4;
  f32x4 acc0 = {0.f, 0.f, 0.f, 0.f};
  f32x4 acc1 = {0.f, 0.f, 0.f, 0.f};
  f32x4 acc2 = {0.f, 0.f, 0.f, 0.f};
#pragma unroll
  for (int ks = 0; ks < 4; ks++) {
    bf16x8 a = *(const bf16x8*)&As[w * 16 + mrow][ks * 16 + g * 4];
    bf16x8 b0v = *(const bf16x8*)&Wt[mrow][ks * 16 + g * 4];
    bf16x8 b1v = *(const bf16x8*)&Wt[16 + mrow][ks * 16 + g * 4];
    bf16x8 b2v = *(const bf16x8*)&Wt[32 + mrow][ks * 16 + g * 4];
    acc0 = __builtin_amdgcn_mfma_f32_16x16x32_bf16(a, b0v, acc0, 0, 0, 0);
    acc1 = __builtin_amdgcn_mfma_f32_16x16x32_bf16(a, b1v, acc1, 0, 0, 0);
    acc2 = __builtin_amdgcn_mfma_f32_16x16x32_bf16(a, b2v, acc2, 0, 0, 0);
  }
  int col = lane & 15;
  float as0 = (col < OD)      ? a_src1[col]      : 0.f;
  float as1 = (16 + col < OD) ? a_src1[16 + col] : 0.f;
  float as2 = (32 + col < OD) ? a_src1[32 + col] : 0.f;
  float ad0 = (col < OD)      ? a_dst1[col]      : 0.f;
  float ad1 = (16 + col < OD) ? a_dst1[16 + col] : 0.f;
  float ad2 = (32 + col < OD) ? a_dst1[32 + col] : 0.f;
#pragma unroll
  for (int reg = 0; reg < 4; reg++) {
    int r = rowbase + w * 16 + g * 4 + reg;
    float v0 = acc0[reg], v1 = acc1[reg], v2 = acc2[reg];
    float ps = v0 * as0 + v1 * as1 + v2 * as2;
    float pd = v0 * ad0 + v1 * ad1 + v2 * ad2;
#pragma unroll
    for (int mk = 1; mk < 16; mk <<= 1) { ps += __shfl_xor(ps, mk); pd += __shfl_xor(pd, mk); }
    bool rok = r < NN;
    if ((lane & 15) == 0 && rok) { asrc1[r] = ps; adst1[r] = pd; }
    float n0 = __shfl_xor(v0, 1), n1 = __shfl_xor(v1, 1), n2 = __shfl_xor(v2, 1);
    if (!(col & 1) && rok) {
      h1b[(size_t)r * 20 + ((col) >> 1)]      = pack_bf16(v0, n0);
      h1b[(size_t)r * 20 + ((16 + col) >> 1)] = pack_bf16(v1, n1);
      if (32 + col < OD) h1b[(size_t)r * 20 + ((32 + col) >> 1)] = pack_bf16(v2, n2);
    }
  }
}

// ---- layer-1 aggregate: one wave/node; 6 edges x 10 lanes, uint2 loads ----
__global__ __launch_bounds__(256) void agg1_kernel(const int* __restrict__ csr_src,
                                                   const int* __restrict__ rowptr,
                                                   const float* __restrict__ asrc1,
                                                   const float* __restrict__ adst1,
                                                   const unsigned* __restrict__ h1b,
                                                   const float* __restrict__ b1,
                                                   float* __restrict__ out) {
  __shared__ float ws[4][64];
  __shared__ int   ss[4][64];
  int t = threadIdx.x;
  int lane = t & 63, wv = t >> 6;
  int n = blockIdx.x * 4 + wv;
  if (n >= NN) return;
  int start = rowptr[n], end = rowptr[n + 1];
  float ad = adst1[n];
  int esub = lane / 10;          // 0..5 for lanes 0..59
  int c2   = lane - esub * 10;   // u32-pair index; channels 4*c2..4*c2+3
  float dsum = 0.f;
  float acc0 = 0.f, acc1 = 0.f, acc2 = 0.f, acc3 = 0.f;
  for (int base = start; base < end; base += 64) {
    int cnt = min(64, end - base);
    if (lane < cnt) {
      int s = csr_src[base + lane];
      float w = __expf(lrelu(asrc1[s] + ad));
      dsum += w;
      ss[wv][lane] = s;
      ws[wv][lane] = w;
    }
    __builtin_amdgcn_wave_barrier();
    if (lane < 60) {
      int e = esub;
      for (; e + 18 < cnt; e += 24) {
        int s0 = ss[wv][e], s1 = ss[wv][e + 6], s2 = ss[wv][e + 12], s3 = ss[wv][e + 18];
        uint2 u0 = *(const uint2*)&h1b[(size_t)s0 * 20 + c2 * 2];
        uint2 u1 = *(const uint2*)&h1b[(size_t)s1 * 20 + c2 * 2];
        uint2 u2 = *(const uint2*)&h1b[(size_t)s2 * 20 + c2 * 2];
        uint2 u3 = *(const uint2*)&h1b[(size_t)s3 * 20 + c2 * 2];
        float w0 = ws[wv][e], w1 = ws[wv][e + 6], w2 = ws[wv][e + 12], w3 = ws[wv][e + 18];
        acc0 += w0 * bf16_lo(u0.x); acc1 += w0 * bf16_hi(u0.x);
        acc2 += w0 * bf16_lo(u0.y); acc3 += w0 * bf16_hi(u0.y);
        acc0 += w1 * bf16_lo(u1.x); acc1 += w1 * bf16_hi(u1.x);
        acc2 += w1 * bf16_lo(u1.y); acc3 += w1 * bf16_hi(u1.y);
        acc0 += w2 * bf16_lo(u2.x); acc1 += w2 * bf16_hi(u2.x);
        acc2 += w2 * bf16_lo(u2.y); acc3 += w2 * bf16_hi(u2.y);
        acc0 += w3 * bf16_lo(u3.x); acc1 += w3 * bf16_hi(u3.x);
        acc2 += w3 * bf16_lo(u3.y); acc3 += w3 * bf16_hi(u3.y);
      }
      for (; e < cnt; e += 6) {
        int s = ss[wv][e];
        float w = ws[wv][e];
        uint2 u = *(const uint2*)&h1b[(size_t)s * 20 + c2 * 2];
        acc0 += w * bf16_lo(u.x); acc1 += w * bf16_hi(u.x);
        acc2 += w * bf16_lo(u.y); acc3 += w * bf16_hi(u.y);
      }
    }
    __builtin_amdgcn_wave_barrier();
  }
#pragma unroll
  for (int mk = 1; mk < 64; mk <<= 1) dsum += __shfl_xor(dsum, mk);
  float rd = 1.f / dsum;
  // combine the 6 esub groups down to lanes 0..9 (read ALL partials before summing)
  float p01 = __shfl(acc0, lane + 10), p02 = __shfl(acc0, lane + 20);
  float p03 = __shfl(acc0, lane + 30), p04 = __shfl(acc0, lane + 40);
  float p05 = __shfl(acc0, lane + 50);
  float p11 = __shfl(acc1, lane + 10), p12 = __shfl(acc1, lane + 20);
  float p13 = __shfl(acc1, lane + 30), p14 = __shfl(acc1, lane + 40);
  float p15 = __shfl(acc1, lane + 50);
  float p21 = __shfl(acc2, lane + 10), p22 = __shfl(acc2, lane + 20);
  float p23 = __shfl(acc2, lane + 30), p24 = __shfl(acc2, lane + 40);
  float p25 = __shfl(acc2, lane + 50);
  float p31 = __shfl(acc3, lane + 10), p32 = __shfl(acc3, lane + 20);
  float p33 = __shfl(acc3, lane + 30), p34 = __shfl(acc3, lane + 40);
  float p35 = __shfl(acc3, lane + 50);
  if (lane < 10) {
    float t0 = acc0 + p01 + p02 + p03 + p04 + p05;
    float t1 = acc1 + p11 + p12 + p13 + p14 + p15;
    float t2 = acc2 + p21 + p22 + p23 + p24 + p25;
    float t3 = acc3 + p31 + p32 + p33 + p34 + p35;
    float4 bv = *(const float4*)&b1[lane * 4];
    float4 o;
    o.x = t0 * rd + bv.x;
    o.y = t1 * rd + bv.y;
    o.z = t2 * rd + bv.z;
    o.w = t3 * rd + bv.w;
    *(float4*)&out[(size_t)n * 40 + lane * 4] = o;
  }
}

// ---------------- host launch ----------------
extern "C" void kernel_launch(void* const* d_in, const int* in_sizes, int n_in,
                              void* d_out, int out_size, void* d_ws, size_t ws_size,
                              hipStream_t stream) {
  const float* x       = (const float*)d_in[0];
  const int*   ei      = (const int*)d_in[1];
  const float* W0      = (const float*)d_in[2];
  const float* a_src0  = (const float*)d_in[3];
  const float* a_dst0  = (const float*)d_in[4];
  const float* b0      = (const float*)d_in[5];
  const float* gamma0  = (const float*)d_in[6];
  const float* beta0   = (const float*)d_in[7];
  const float* W1      = (const float*)d_in[8];
  const float* a_src1  = (const float*)d_in[9];
  const float* a_dst1  = (const float*)d_in[10];
  const float* b1      = (const float*)d_in[11];
  float* out = (float*)d_out;

  char* ws = (char*)d_ws;
  size_t off = 0;
  auto alloc = [&](size_t bytes) {
    void* p = ws + off;
    off += (bytes + 255) & ~(size_t)255;
    return p;
  };
  // zero-region first: deg, bnsumB, bnsqB (contiguous)
  int*   deg      = (int*)alloc((size_t)NN * 4);
  float* bnsumB   = (float*)alloc(NBKT * 128 * 4);
  float* bnsqB    = (float*)alloc(NBKT * 128 * 4);
  unsigned* h0b   = (unsigned*)alloc((size_t)NN * 64 * 4);   // bf16x2
  unsigned* agg0b = (unsigned*)alloc((size_t)NN * 64 * 4);   // bf16x2
  unsigned* h1b   = (unsigned*)alloc((size_t)NN * 20 * 4);   // bf16x2
  float* asrc0    = (float*)alloc((size_t)NN * 4 * 4);
  float* adst0    = (float*)alloc((size_t)NN * 4 * 4);
  float* asrc1    = (float*)alloc((size_t)NN * 4);
  float* adst1    = (float*)alloc((size_t)NN * 4);
  int*   rowptr   = (int*)alloc((size_t)(NN + 1) * 4);
  int*   scanned  = (int*)alloc((size_t)NN * 4);
  int*   csr      = (int*)alloc((size_t)ETOT * 4);
  int*   rank     = (int*)alloc((size_t)ETOT * 4);
  int*   bsums    = (int*)alloc(512 * 4);
  unsigned* w0t   = (unsigned*)alloc(128 * 64 * 4);
  (void)ws_size; (void)in_sizes; (void)n_in; (void)out_size;

  size_t zbytes = (char*)(bnsqB + NBKT * 128) - (char*)deg;
  hipMemsetAsync(deg, 0, zbytes, stream);

  const int NB = (NN + 255) / 256;
  const int e4grid = (ETOT / 4 + 255) / 256;

  prep_kernel<<<e4grid, 256, 0, stream>>>(W0, w0t, ei, deg, rank);
  gemm0_kernel<<<(NN + 63) / 64, 256, 0, stream>>>(x, w0t, a_src0, a_dst0, h0b, asrc0, adst0);
  scanA_kernel<<<NB, 256, 0, stream>>>(deg, scanned, bsums);
  scanB_kernel<<<1, 512, 0, stream>>>(bsums, NB);
  scanC_kernel<<<NB, 256, 0, stream>>>(scanned, deg, bsums, rowptr);
  scatter_kernel<<<e4grid, 256, 0, stream>>>(ei, rowptr, rank, csr);
  for (int h = 0; h < 4; h++) {
    agg0h_kernel<<<NN / 16, 256, 0, stream>>>(csr, rowptr, asrc0, adst0, h0b, b0, agg0b,
                                              bnsumB, bnsqB, h);
  }
  gemm1_kernel<<<(NN + 63) / 64, 256, 0, stream>>>(agg0b, bnsumB, bnsqB, gamma0, beta0,
                                                   W1, a_src1, a_dst1, h1b, asrc1, adst1);
  agg1_kernel<<<(NN + 3) / 4, 256, 0, stream>>>(csr, rowptr, asrc1, adst1, h1b, b1, out);
}

// Round 12
// 301.851 us; speedup vs baseline: 1.2984x; 1.2984x over previous
//
#include <hip/hip_runtime.h>
#include <hip/hip_bf16.h>
#include <math.h>

#define NN   100000
#define EE   1600000
#define ETOT (NN + EE)
#define IND  128
#define HD   128    // HEADS*HID
#define OD   40
#define NEG  0.2f
#define BNEPS 1e-5f
#define NBKT 16     // BN-stat buckets

typedef __attribute__((ext_vector_type(8))) short bf16x8;
typedef __attribute__((ext_vector_type(4))) float f32x4;

__device__ __forceinline__ float lrelu(float x) { return x > 0.f ? x : NEG * x; }

__device__ __forceinline__ unsigned pack_bf16(float a, float b) {
  unsigned ua = __float_as_uint(a), ub = __float_as_uint(b);
  ua = (ua + 0x7fffu + ((ua >> 16) & 1u)) >> 16;
  ub = (ub + 0x7fffu + ((ub >> 16) & 1u)) >> 16;
  return ua | (ub << 16);
}
__device__ __forceinline__ float bf16_lo(unsigned v) { return __uint_as_float(v << 16); }
__device__ __forceinline__ float bf16_hi(unsigned v) { return __uint_as_float(v & 0xffff0000u); }

// ---- prep: W0 transpose-pack (first 8192 threads) + degrank 8 edges/thread ----
// ETOT and EE are multiples of 8 -> an 8-chunk never straddles the self-loop boundary.
__global__ void prep_kernel(const float* __restrict__ W0, unsigned* __restrict__ w0t,
                            const int* __restrict__ ei, int* __restrict__ deg,
                            int* __restrict__ rank) {
  int gid = blockIdx.x * blockDim.x + threadIdx.x;
  if (gid < 128 * 64) {
    int n = gid & 127, kp = gid >> 7;
    float lo = W0[(size_t)(2 * kp) * 128 + n];
    float hi = W0[(size_t)(2 * kp + 1) * 128 + n];
    w0t[n * 64 + kp] = pack_bf16(lo, hi);
  }
  int i8 = gid * 8;
  if (i8 >= ETOT) return;
  int4 dA, dB;
  if (i8 < EE) {
    dA = *(const int4*)&ei[EE + i8];
    dB = *(const int4*)&ei[EE + i8 + 4];
  } else {
    int b = i8 - EE;
    dA = make_int4(b, b + 1, b + 2, b + 3);
    dB = make_int4(b + 4, b + 5, b + 6, b + 7);
  }
  int4 rA, rB;
  rA.x = atomicAdd(&deg[dA.x], 1);
  rA.y = atomicAdd(&deg[dA.y], 1);
  rA.z = atomicAdd(&deg[dA.z], 1);
  rA.w = atomicAdd(&deg[dA.w], 1);
  rB.x = atomicAdd(&deg[dB.x], 1);
  rB.y = atomicAdd(&deg[dB.y], 1);
  rB.z = atomicAdd(&deg[dB.z], 1);
  rB.w = atomicAdd(&deg[dB.w], 1);
  *(int4*)&rank[i8] = rA;
  *(int4*)&rank[i8 + 4] = rB;
}

// ---- GEMM0 via MFMA + fused alpha logits ----
__global__ __launch_bounds__(256) void gemm0_kernel(const float* __restrict__ x,
                                                    const unsigned* __restrict__ w0t,
                                                    const float* __restrict__ a_src0,
                                                    const float* __restrict__ a_dst0,
                                                    unsigned* __restrict__ h0b,
                                                    float* __restrict__ asrc0,
                                                    float* __restrict__ adst0) {
  __shared__ __align__(16) unsigned As[64][68];   // bf16x2 [row][k/2]
  __shared__ __align__(16) unsigned Wt[128][68];  // bf16x2 [col][k/2]
  int t = threadIdx.x;
  int rowbase = blockIdx.x * 64;
  for (int idx = t; idx < 128 * 64; idx += 256) {
    Wt[idx >> 6][idx & 63] = w0t[idx];
  }
  for (int idx = t; idx < 64 * 64; idx += 256) {
    int row = idx >> 6, kp = idx & 63;
    int r = rowbase + row;
    int rc = r < NN ? r : NN - 1;
    float2 v = *(const float2*)&x[(size_t)rc * 128 + kp * 2];
    As[row][kp] = pack_bf16(v.x, v.y);
  }
  __syncthreads();

  int lane = t & 63, w = t >> 6;
  int mrow = lane & 15, g = lane >> 4;
  f32x4 acc[8];
#pragma unroll
  for (int nt = 0; nt < 8; nt++) acc[nt] = (f32x4){0.f, 0.f, 0.f, 0.f};
#pragma unroll
  for (int ks = 0; ks < 4; ks++) {
    bf16x8 a = *(const bf16x8*)&As[w * 16 + mrow][ks * 16 + g * 4];
#pragma unroll
    for (int nt = 0; nt < 8; nt++) {
      bf16x8 b = *(const bf16x8*)&Wt[nt * 16 + mrow][ks * 16 + g * 4];
      acc[nt] = __builtin_amdgcn_mfma_f32_16x16x32_bf16(a, b, acc[nt], 0, 0, 0);
    }
  }
  int col = lane & 15;
  float as_[8], ad_[8];
#pragma unroll
  for (int nt = 0; nt < 8; nt++) {
    as_[nt] = a_src0[nt * 16 + col];
    ad_[nt] = a_dst0[nt * 16 + col];
  }
#pragma unroll
  for (int reg = 0; reg < 4; reg++) {
    int r = rowbase + w * 16 + g * 4 + reg;
    bool rok = r < NN;
    float hs0 = acc[0][reg] * as_[0] + acc[1][reg] * as_[1];
    float hs1 = acc[2][reg] * as_[2] + acc[3][reg] * as_[3];
    float hs2 = acc[4][reg] * as_[4] + acc[5][reg] * as_[5];
    float hs3 = acc[6][reg] * as_[6] + acc[7][reg] * as_[7];
    float hd0 = acc[0][reg] * ad_[0] + acc[1][reg] * ad_[1];
    float hd1 = acc[2][reg] * ad_[2] + acc[3][reg] * ad_[3];
    float hd2 = acc[4][reg] * ad_[4] + acc[5][reg] * ad_[5];
    float hd3 = acc[6][reg] * ad_[6] + acc[7][reg] * ad_[7];
#pragma unroll
    for (int mk = 1; mk < 16; mk <<= 1) {
      hs0 += __shfl_xor(hs0, mk); hs1 += __shfl_xor(hs1, mk);
      hs2 += __shfl_xor(hs2, mk); hs3 += __shfl_xor(hs3, mk);
      hd0 += __shfl_xor(hd0, mk); hd1 += __shfl_xor(hd1, mk);
      hd2 += __shfl_xor(hd2, mk); hd3 += __shfl_xor(hd3, mk);
    }
    if ((lane & 15) == 0 && rok) {
      asrc0[r * 4 + 0] = hs0; asrc0[r * 4 + 1] = hs1;
      asrc0[r * 4 + 2] = hs2; asrc0[r * 4 + 3] = hs3;
      adst0[r * 4 + 0] = hd0; adst0[r * 4 + 1] = hd1;
      adst0[r * 4 + 2] = hd2; adst0[r * 4 + 3] = hd3;
    }
#pragma unroll
    for (int nt = 0; nt < 8; nt++) {
      float v = acc[nt][reg];
      float nv = __shfl_xor(v, 1);
      if (!(col & 1) && rok) h0b[(size_t)r * 64 + nt * 8 + (col >> 1)] = pack_bf16(v, nv);
    }
  }
}

// ---------------- CSR scans ----------------
__global__ __launch_bounds__(256) void scanA_kernel(const int* __restrict__ deg,
                                                    int* __restrict__ scanned,
                                                    int* __restrict__ blocksums) {
  __shared__ int s[256];
  int t = threadIdx.x;
  int i = blockIdx.x * 256 + t;
  int v = (i < NN) ? deg[i] : 0;
  s[t] = v;
  __syncthreads();
  for (int off = 1; off < 256; off <<= 1) {
    int add = (t >= off) ? s[t - off] : 0;
    __syncthreads();
    s[t] += add;
    __syncthreads();
  }
  if (i < NN) scanned[i] = s[t];
  if (t == 255) blocksums[blockIdx.x] = s[255];
}

__global__ __launch_bounds__(512) void scanB_kernel(int* __restrict__ blocksums, int NB) {
  __shared__ int s[512];
  int t = threadIdx.x;
  int v = (t < NB) ? blocksums[t] : 0;
  s[t] = v;
  __syncthreads();
  for (int off = 1; off < 512; off <<= 1) {
    int add = (t >= off) ? s[t - off] : 0;
    __syncthreads();
    s[t] += add;
    __syncthreads();
  }
  if (t < NB) blocksums[t] = s[t] - v;  // exclusive block offset
}

__global__ __launch_bounds__(256) void scanC_kernel(const int* __restrict__ scanned,
                                                    const int* __restrict__ deg,
                                                    const int* __restrict__ blocksums,
                                                    int* __restrict__ rowptr) {
  int i = blockIdx.x * 256 + threadIdx.x;
  if (i < NN) rowptr[i] = blocksums[blockIdx.x] + scanned[i] - deg[i];
  if (i == 0) rowptr[NN] = ETOT;
}

// 8 edges/thread scatter
__global__ void scatter_kernel(const int* __restrict__ ei, const int* __restrict__ rowptr,
                               const int* __restrict__ rank, int* __restrict__ csr_src) {
  int i8 = (blockIdx.x * blockDim.x + threadIdx.x) * 8;
  if (i8 >= ETOT) return;
  int4 sA, dA, sB, dB;
  if (i8 < EE) {
    sA = *(const int4*)&ei[i8];
    sB = *(const int4*)&ei[i8 + 4];
    dA = *(const int4*)&ei[EE + i8];
    dB = *(const int4*)&ei[EE + i8 + 4];
  } else {
    int b = i8 - EE;
    sA = make_int4(b, b + 1, b + 2, b + 3);
    sB = make_int4(b + 4, b + 5, b + 6, b + 7);
    dA = sA; dB = sB;
  }
  int4 rA = *(const int4*)&rank[i8];
  int4 rB = *(const int4*)&rank[i8 + 4];
  int p0 = rowptr[dA.x] + rA.x;
  int p1 = rowptr[dA.y] + rA.y;
  int p2 = rowptr[dA.z] + rA.z;
  int p3 = rowptr[dA.w] + rA.w;
  int p4 = rowptr[dB.x] + rB.x;
  int p5 = rowptr[dB.y] + rB.y;
  int p6 = rowptr[dB.z] + rB.z;
  int p7 = rowptr[dB.w] + rB.w;
  csr_src[p0] = sA.x;
  csr_src[p1] = sA.y;
  csr_src[p2] = sA.z;
  csr_src[p3] = sA.w;
  csr_src[p4] = sB.x;
  csr_src[p5] = sB.y;
  csr_src[p6] = sB.z;
  csr_src[p7] = sB.w;
}

// ---- layer-0 aggregate (16 lanes/node, 4-deep) + FUSED BN-stat accumulation ----
// NN is a multiple of 16 -> exactly 6250 full blocks, no early returns.
__global__ __launch_bounds__(256) void agg0_kernel(const int* __restrict__ csr_src,
                                                   const int* __restrict__ rowptr,
                                                   const float* __restrict__ asrc0,
                                                   const float* __restrict__ adst0,
                                                   const unsigned* __restrict__ h0b,
                                                   const float* __restrict__ b0,
                                                   unsigned* __restrict__ agg0b,
                                                   float* __restrict__ bnsumB,
                                                   float* __restrict__ bnsqB) {
  __shared__ float ws[16][4][17];   // [group][head][edge]
  __shared__ int   ss[16][16];
  __shared__ float Lsum[4][16][8], Lsq[4][16][8];
  int t = threadIdx.x;
  int grp = t >> 4;        // node group 0..15
  int p   = t & 15;        // owns channels 8p..8p+7
  int n = blockIdx.x * 16 + grp;
  int start = rowptr[n], end = rowptr[n + 1];
  float4 ad = *(const float4*)&adst0[(size_t)n * 4];
  int head = p >> 2;
  float a0 = 0.f, a1 = 0.f, a2 = 0.f, a3 = 0.f, a4 = 0.f, a5 = 0.f, a6 = 0.f, a7 = 0.f;
  float d0 = 0.f, d1 = 0.f, d2 = 0.f, d3 = 0.f;

  for (int base = start; base < end; base += 16) {
    int cnt = min(16, end - base);
    if (p < cnt) {
      int s = csr_src[base + p];
      float4 as = *(const float4*)&asrc0[(size_t)s * 4];
      float w0 = __expf(lrelu(as.x + ad.x));
      float w1 = __expf(lrelu(as.y + ad.y));
      float w2 = __expf(lrelu(as.z + ad.z));
      float w3 = __expf(lrelu(as.w + ad.w));
      d0 += w0; d1 += w1; d2 += w2; d3 += w3;
      ss[grp][p] = s;
      ws[grp][0][p] = w0;
      ws[grp][1][p] = w1;
      ws[grp][2][p] = w2;
      ws[grp][3][p] = w3;
    }
    __builtin_amdgcn_wave_barrier();
    for (int eb = 0; eb < cnt; eb += 4) {
      int e0 = eb, e1 = eb + 1, e2 = eb + 2, e3 = eb + 3;
      float w0 = ws[grp][head][e0];
      float w1 = (e1 < cnt) ? ws[grp][head][e1] : 0.f;
      float w2 = (e2 < cnt) ? ws[grp][head][e2] : 0.f;
      float w3 = (e3 < cnt) ? ws[grp][head][e3] : 0.f;
      int s0 = ss[grp][e0];
      int s1 = ss[grp][(e1 < cnt) ? e1 : e0];
      int s2 = ss[grp][(e2 < cnt) ? e2 : e0];
      int s3 = ss[grp][(e3 < cnt) ? e3 : e0];
      uint4 h0v = *(const uint4*)&h0b[(size_t)s0 * 64 + p * 4];
      uint4 h1v = *(const uint4*)&h0b[(size_t)s1 * 64 + p * 4];
      uint4 h2v = *(const uint4*)&h0b[(size_t)s2 * 64 + p * 4];
      uint4 h3v = *(const uint4*)&h0b[(size_t)s3 * 64 + p * 4];
      a0 += w0 * bf16_lo(h0v.x); a1 += w0 * bf16_hi(h0v.x);
      a2 += w0 * bf16_lo(h0v.y); a3 += w0 * bf16_hi(h0v.y);
      a4 += w0 * bf16_lo(h0v.z); a5 += w0 * bf16_hi(h0v.z);
      a6 += w0 * bf16_lo(h0v.w); a7 += w0 * bf16_hi(h0v.w);
      a0 += w1 * bf16_lo(h1v.x); a1 += w1 * bf16_hi(h1v.x);
      a2 += w1 * bf16_lo(h1v.y); a3 += w1 * bf16_hi(h1v.y);
      a4 += w1 * bf16_lo(h1v.z); a5 += w1 * bf16_hi(h1v.z);
      a6 += w1 * bf16_lo(h1v.w); a7 += w1 * bf16_hi(h1v.w);
      a0 += w2 * bf16_lo(h2v.x); a1 += w2 * bf16_hi(h2v.x);
      a2 += w2 * bf16_lo(h2v.y); a3 += w2 * bf16_hi(h2v.y);
      a4 += w2 * bf16_lo(h2v.z); a5 += w2 * bf16_hi(h2v.z);
      a6 += w2 * bf16_lo(h2v.w); a7 += w2 * bf16_hi(h2v.w);
      a0 += w3 * bf16_lo(h3v.x); a1 += w3 * bf16_hi(h3v.x);
      a2 += w3 * bf16_lo(h3v.y); a3 += w3 * bf16_hi(h3v.y);
      a4 += w3 * bf16_lo(h3v.z); a5 += w3 * bf16_hi(h3v.z);
      a6 += w3 * bf16_lo(h3v.w); a7 += w3 * bf16_hi(h3v.w);
    }
    __builtin_amdgcn_wave_barrier();
  }
#pragma unroll
  for (int mk = 1; mk < 16; mk <<= 1) {
    d0 += __shfl_xor(d0, mk);
    d1 += __shfl_xor(d1, mk);
    d2 += __shfl_xor(d2, mk);
    d3 += __shfl_xor(d3, mk);
  }
  float dh = head == 0 ? d0 : head == 1 ? d1 : head == 2 ? d2 : d3;
  float rd = 1.f / dh;
  int c = p * 8;
  float4 b1v = *(const float4*)&b0[c];
  float4 b2v = *(const float4*)&b0[c + 4];
  float o0 = a0 * rd + b1v.x, o1 = a1 * rd + b1v.y;
  float o2 = a2 * rd + b1v.z, o3 = a3 * rd + b1v.w;
  float o4 = a4 * rd + b2v.x, o5 = a5 * rd + b2v.y;
  float o6 = a6 * rd + b2v.z, o7 = a7 * rd + b2v.w;
  uint4 o;
  o.x = pack_bf16(o0, o1);
  o.y = pack_bf16(o2, o3);
  o.z = pack_bf16(o4, o5);
  o.w = pack_bf16(o6, o7);
  *(uint4*)&agg0b[(size_t)n * 64 + p * 4] = o;

  // fused BN stats: reduce the 4 groups within this wave, then LDS, then bucketed atomics
  float s0 = o0, s1 = o1, s2 = o2, s3 = o3, s4 = o4, s5 = o5, s6 = o6, s7 = o7;
  float q0 = o0 * o0, q1 = o1 * o1, q2 = o2 * o2, q3 = o3 * o3;
  float q4 = o4 * o4, q5 = o5 * o5, q6 = o6 * o6, q7 = o7 * o7;
#pragma unroll
  for (int mk = 16; mk < 64; mk <<= 1) {
    s0 += __shfl_xor(s0, mk); s1 += __shfl_xor(s1, mk);
    s2 += __shfl_xor(s2, mk); s3 += __shfl_xor(s3, mk);
    s4 += __shfl_xor(s4, mk); s5 += __shfl_xor(s5, mk);
    s6 += __shfl_xor(s6, mk); s7 += __shfl_xor(s7, mk);
    q0 += __shfl_xor(q0, mk); q1 += __shfl_xor(q1, mk);
    q2 += __shfl_xor(q2, mk); q3 += __shfl_xor(q3, mk);
    q4 += __shfl_xor(q4, mk); q5 += __shfl_xor(q5, mk);
    q6 += __shfl_xor(q6, mk); q7 += __shfl_xor(q7, mk);
  }
  int lane = t & 63, wv = t >> 6;
  if (lane < 16) {
    Lsum[wv][lane][0] = s0; Lsum[wv][lane][1] = s1;
    Lsum[wv][lane][2] = s2; Lsum[wv][lane][3] = s3;
    Lsum[wv][lane][4] = s4; Lsum[wv][lane][5] = s5;
    Lsum[wv][lane][6] = s6; Lsum[wv][lane][7] = s7;
    Lsq[wv][lane][0] = q0; Lsq[wv][lane][1] = q1;
    Lsq[wv][lane][2] = q2; Lsq[wv][lane][3] = q3;
    Lsq[wv][lane][4] = q4; Lsq[wv][lane][5] = q5;
    Lsq[wv][lane][6] = q6; Lsq[wv][lane][7] = q7;
  }
  __syncthreads();
  if (t < 128) {
    int pp = t >> 3, jj = t & 7;
    float s = Lsum[0][pp][jj] + Lsum[1][pp][jj] + Lsum[2][pp][jj] + Lsum[3][pp][jj];
    float q = Lsq[0][pp][jj] + Lsq[1][pp][jj] + Lsq[2][pp][jj] + Lsq[3][pp][jj];
    int bkt = blockIdx.x & (NBKT - 1);
    atomicAdd(&bnsumB[bkt * 128 + t], s);
    atomicAdd(&bnsqB[bkt * 128 + t], q);
  }
}

// ---- GEMM1 via MFMA: BN finalize in prologue, fused BN+ELU, alpha1, bf16 h1 ----
__global__ __launch_bounds__(256) void gemm1_kernel(const unsigned* __restrict__ agg0b,
                                                    const float* __restrict__ bnsumB,
                                                    const float* __restrict__ bnsqB,
                                                    const float* __restrict__ gamma,
                                                    const float* __restrict__ beta,
                                                    const float* __restrict__ W1,
                                                    const float* __restrict__ a_src1,
                                                    const float* __restrict__ a_dst1,
                                                    unsigned* __restrict__ h1b,
                                                    float* __restrict__ asrc1,
                                                    float* __restrict__ adst1) {
  __shared__ __align__(16) unsigned As[64][68];
  __shared__ __align__(16) unsigned Wt[48][68];
  __shared__ float bnsc[128], bnsh[128];
  int t = threadIdx.x;
  int rowbase = blockIdx.x * 64;

  if (t < 128) {
    float s = 0.f, q = 0.f;
#pragma unroll
    for (int k = 0; k < NBKT; k++) {
      s += bnsumB[k * 128 + t];
      q += bnsqB[k * 128 + t];
    }
    float mu = s / (float)NN;
    float var = q / (float)NN - mu * mu;
    float sc = gamma[t] / sqrtf(var + BNEPS);
    bnsc[t] = sc;
    bnsh[t] = beta[t] - mu * sc;
  }
  for (int idx = t; idx < 48 * 64; idx += 256) {
    int c = idx >> 6, kp = idx & 63;
    float lo = (c < OD) ? W1[(size_t)(2 * kp) * OD + c] : 0.f;
    float hi = (c < OD) ? W1[(size_t)(2 * kp + 1) * OD + c] : 0.f;
    Wt[c][kp] = pack_bf16(lo, hi);
  }
  __syncthreads();
  for (int idx = t; idx < 64 * 16; idx += 256) {
    int row = idx >> 4, c4 = idx & 15;
    int r = rowbase + row;
    int rc = r < NN ? r : NN - 1;
    int k = c4 * 8;
    uint4 hv = *(const uint4*)&agg0b[(size_t)rc * 64 + c4 * 4];
    float y0 = bf16_lo(hv.x) * bnsc[k + 0] + bnsh[k + 0];
    float y1 = bf16_hi(hv.x) * bnsc[k + 1] + bnsh[k + 1];
    float y2 = bf16_lo(hv.y) * bnsc[k + 2] + bnsh[k + 2];
    float y3 = bf16_hi(hv.y) * bnsc[k + 3] + bnsh[k + 3];
    float y4 = bf16_lo(hv.z) * bnsc[k + 4] + bnsh[k + 4];
    float y5 = bf16_hi(hv.z) * bnsc[k + 5] + bnsh[k + 5];
    float y6 = bf16_lo(hv.w) * bnsc[k + 6] + bnsh[k + 6];
    float y7 = bf16_hi(hv.w) * bnsc[k + 7] + bnsh[k + 7];
    y0 = y0 > 0.f ? y0 : expm1f(y0);
    y1 = y1 > 0.f ? y1 : expm1f(y1);
    y2 = y2 > 0.f ? y2 : expm1f(y2);
    y3 = y3 > 0.f ? y3 : expm1f(y3);
    y4 = y4 > 0.f ? y4 : expm1f(y4);
    y5 = y5 > 0.f ? y5 : expm1f(y5);
    y6 = y6 > 0.f ? y6 : expm1f(y6);
    y7 = y7 > 0.f ? y7 : expm1f(y7);
    As[row][c4 * 4 + 0] = pack_bf16(y0, y1);
    As[row][c4 * 4 + 1] = pack_bf16(y2, y3);
    As[row][c4 * 4 + 2] = pack_bf16(y4, y5);
    As[row][c4 * 4 + 3] = pack_bf16(y6, y7);
  }
  __syncthreads();

  int lane = t & 63, w = t >> 6;
  int mrow = lane & 15, g = lane >> 4;
  f32x4 acc0 = {0.f, 0.f, 0.f, 0.f};
  f32x4 acc1 = {0.f, 0.f, 0.f, 0.f};
  f32x4 acc2 = {0.f, 0.f, 0.f, 0.f};
#pragma unroll
  for (int ks = 0; ks < 4; ks++) {
    bf16x8 a = *(const bf16x8*)&As[w * 16 + mrow][ks * 16 + g * 4];
    bf16x8 b0v = *(const bf16x8*)&Wt[mrow][ks * 16 + g * 4];
    bf16x8 b1v = *(const bf16x8*)&Wt[16 + mrow][ks * 16 + g * 4];
    bf16x8 b2v = *(const bf16x8*)&Wt[32 + mrow][ks * 16 + g * 4];
    acc0 = __builtin_amdgcn_mfma_f32_16x16x32_bf16(a, b0v, acc0, 0, 0, 0);
    acc1 = __builtin_amdgcn_mfma_f32_16x16x32_bf16(a, b1v, acc1, 0, 0, 0);
    acc2 = __builtin_amdgcn_mfma_f32_16x16x32_bf16(a, b2v, acc2, 0, 0, 0);
  }
  int col = lane & 15;
  float as0 = (col < OD)      ? a_src1[col]      : 0.f;
  float as1 = (16 + col < OD) ? a_src1[16 + col] : 0.f;
  float as2 = (32 + col < OD) ? a_src1[32 + col] : 0.f;
  float ad0 = (col < OD)      ? a_dst1[col]      : 0.f;
  float ad1 = (16 + col < OD) ? a_dst1[16 + col] : 0.f;
  float ad2 = (32 + col < OD) ? a_dst1[32 + col] : 0.f;
#pragma unroll
  for (int reg = 0; reg < 4; reg++) {
    int r = rowbase + w * 16 + g * 4 + reg;
    float v0 = acc0[reg], v1 = acc1[reg], v2 = acc2[reg];
    float ps = v0 * as0 + v1 * as1 + v2 * as2;
    float pd = v0 * ad0 + v1 * ad1 + v2 * ad2;
#pragma unroll
    for (int mk = 1; mk < 16; mk <<= 1) { ps += __shfl_xor(ps, mk); pd += __shfl_xor(pd, mk); }
    bool rok = r < NN;
    if ((lane & 15) == 0 && rok) { asrc1[r] = ps; adst1[r] = pd; }
    float n0 = __shfl_xor(v0, 1), n1 = __shfl_xor(v1, 1), n2 = __shfl_xor(v2, 1);
    if (!(col & 1) && rok) {
      h1b[(size_t)r * 20 + ((col) >> 1)]      = pack_bf16(v0, n0);
      h1b[(size_t)r * 20 + ((16 + col) >> 1)] = pack_bf16(v1, n1);
      if (32 + col < OD) h1b[(size_t)r * 20 + ((32 + col) >> 1)] = pack_bf16(v2, n2);
    }
  }
}

// ---- layer-1 aggregate: one wave/node; 6 edges x 10 lanes, uint2 loads ----
__global__ __launch_bounds__(256) void agg1_kernel(const int* __restrict__ csr_src,
                                                   const int* __restrict__ rowptr,
                                                   const float* __restrict__ asrc1,
                                                   const float* __restrict__ adst1,
                                                   const unsigned* __restrict__ h1b,
                                                   const float* __restrict__ b1,
                                                   float* __restrict__ out) {
  __shared__ float ws[4][64];
  __shared__ int   ss[4][64];
  int t = threadIdx.x;
  int lane = t & 63, wv = t >> 6;
  int n = blockIdx.x * 4 + wv;
  if (n >= NN) return;
  int start = rowptr[n], end = rowptr[n + 1];
  float ad = adst1[n];
  int esub = lane / 10;          // 0..5 for lanes 0..59
  int c2   = lane - esub * 10;   // u32-pair index; channels 4*c2..4*c2+3
  float dsum = 0.f;
  float acc0 = 0.f, acc1 = 0.f, acc2 = 0.f, acc3 = 0.f;
  for (int base = start; base < end; base += 64) {
    int cnt = min(64, end - base);
    if (lane < cnt) {
      int s = csr_src[base + lane];
      float w = __expf(lrelu(asrc1[s] + ad));
      dsum += w;
      ss[wv][lane] = s;
      ws[wv][lane] = w;
    }
    __builtin_amdgcn_wave_barrier();
    if (lane < 60) {
      int e = esub;
      for (; e + 18 < cnt; e += 24) {
        int s0 = ss[wv][e], s1 = ss[wv][e + 6], s2 = ss[wv][e + 12], s3 = ss[wv][e + 18];
        uint2 u0 = *(const uint2*)&h1b[(size_t)s0 * 20 + c2 * 2];
        uint2 u1 = *(const uint2*)&h1b[(size_t)s1 * 20 + c2 * 2];
        uint2 u2 = *(const uint2*)&h1b[(size_t)s2 * 20 + c2 * 2];
        uint2 u3 = *(const uint2*)&h1b[(size_t)s3 * 20 + c2 * 2];
        float w0 = ws[wv][e], w1 = ws[wv][e + 6], w2 = ws[wv][e + 12], w3 = ws[wv][e + 18];
        acc0 += w0 * bf16_lo(u0.x); acc1 += w0 * bf16_hi(u0.x);
        acc2 += w0 * bf16_lo(u0.y); acc3 += w0 * bf16_hi(u0.y);
        acc0 += w1 * bf16_lo(u1.x); acc1 += w1 * bf16_hi(u1.x);
        acc2 += w1 * bf16_lo(u1.y); acc3 += w1 * bf16_hi(u1.y);
        acc0 += w2 * bf16_lo(u2.x); acc1 += w2 * bf16_hi(u2.x);
        acc2 += w2 * bf16_lo(u2.y); acc3 += w2 * bf16_hi(u2.y);
        acc0 += w3 * bf16_lo(u3.x); acc1 += w3 * bf16_hi(u3.x);
        acc2 += w3 * bf16_lo(u3.y); acc3 += w3 * bf16_hi(u3.y);
      }
      for (; e < cnt; e += 6) {
        int s = ss[wv][e];
        float w = ws[wv][e];
        uint2 u = *(const uint2*)&h1b[(size_t)s * 20 + c2 * 2];
        acc0 += w * bf16_lo(u.x); acc1 += w * bf16_hi(u.x);
        acc2 += w * bf16_lo(u.y); acc3 += w * bf16_hi(u.y);
      }
    }
    __builtin_amdgcn_wave_barrier();
  }
#pragma unroll
  for (int mk = 1; mk < 64; mk <<= 1) dsum += __shfl_xor(dsum, mk);
  float rd = 1.f / dsum;
  // combine the 6 esub groups down to lanes 0..9 (read ALL partials before summing)
  float p01 = __shfl(acc0, lane + 10), p02 = __shfl(acc0, lane + 20);
  float p03 = __shfl(acc0, lane + 30), p04 = __shfl(acc0, lane + 40);
  float p05 = __shfl(acc0, lane + 50);
  float p11 = __shfl(acc1, lane + 10), p12 = __shfl(acc1, lane + 20);
  float p13 = __shfl(acc1, lane + 30), p14 = __shfl(acc1, lane + 40);
  float p15 = __shfl(acc1, lane + 50);
  float p21 = __shfl(acc2, lane + 10), p22 = __shfl(acc2, lane + 20);
  float p23 = __shfl(acc2, lane + 30), p24 = __shfl(acc2, lane + 40);
  float p25 = __shfl(acc2, lane + 50);
  float p31 = __shfl(acc3, lane + 10), p32 = __shfl(acc3, lane + 20);
  float p33 = __shfl(acc3, lane + 30), p34 = __shfl(acc3, lane + 40);
  float p35 = __shfl(acc3, lane + 50);
  if (lane < 10) {
    float t0 = acc0 + p01 + p02 + p03 + p04 + p05;
    float t1 = acc1 + p11 + p12 + p13 + p14 + p15;
    float t2 = acc2 + p21 + p22 + p23 + p24 + p25;
    float t3 = acc3 + p31 + p32 + p33 + p34 + p35;
    float4 bv = *(const float4*)&b1[lane * 4];
    float4 o;
    o.x = t0 * rd + bv.x;
    o.y = t1 * rd + bv.y;
    o.z = t2 * rd + bv.z;
    o.w = t3 * rd + bv.w;
    *(float4*)&out[(size_t)n * 40 + lane * 4] = o;
  }
}

// ---------------- host launch ----------------
extern "C" void kernel_launch(void* const* d_in, const int* in_sizes, int n_in,
                              void* d_out, int out_size, void* d_ws, size_t ws_size,
                              hipStream_t stream) {
  const float* x       = (const float*)d_in[0];
  const int*   ei      = (const int*)d_in[1];
  const float* W0      = (const float*)d_in[2];
  const float* a_src0  = (const float*)d_in[3];
  const float* a_dst0  = (const float*)d_in[4];
  const float* b0      = (const float*)d_in[5];
  const float* gamma0  = (const float*)d_in[6];
  const float* beta0   = (const float*)d_in[7];
  const float* W1      = (const float*)d_in[8];
  const float* a_src1  = (const float*)d_in[9];
  const float* a_dst1  = (const float*)d_in[10];
  const float* b1      = (const float*)d_in[11];
  float* out = (float*)d_out;

  char* ws = (char*)d_ws;
  size_t off = 0;
  auto alloc = [&](size_t bytes) {
    void* p = ws + off;
    off += (bytes + 255) & ~(size_t)255;
    return p;
  };
  // zero-region first: deg, bnsumB, bnsqB (contiguous)
  int*   deg      = (int*)alloc((size_t)NN * 4);
  float* bnsumB   = (float*)alloc(NBKT * 128 * 4);
  float* bnsqB    = (float*)alloc(NBKT * 128 * 4);
  unsigned* h0b   = (unsigned*)alloc((size_t)NN * 64 * 4);   // bf16x2
  unsigned* agg0b = (unsigned*)alloc((size_t)NN * 64 * 4);   // bf16x2
  unsigned* h1b   = (unsigned*)alloc((size_t)NN * 20 * 4);   // bf16x2
  float* asrc0    = (float*)alloc((size_t)NN * 4 * 4);
  float* adst0    = (float*)alloc((size_t)NN * 4 * 4);
  float* asrc1    = (float*)alloc((size_t)NN * 4);
  float* adst1    = (float*)alloc((size_t)NN * 4);
  int*   rowptr   = (int*)alloc((size_t)(NN + 1) * 4);
  int*   scanned  = (int*)alloc((size_t)NN * 4);
  int*   csr      = (int*)alloc((size_t)ETOT * 4);
  int*   rank     = (int*)alloc((size_t)ETOT * 4);
  int*   bsums    = (int*)alloc(512 * 4);
  unsigned* w0t   = (unsigned*)alloc(128 * 64 * 4);
  (void)ws_size; (void)in_sizes; (void)n_in; (void)out_size;

  size_t zbytes = (char*)(bnsqB + NBKT * 128) - (char*)deg;
  hipMemsetAsync(deg, 0, zbytes, stream);

  const int NB = (NN + 255) / 256;
  const int e8grid = (ETOT / 8 + 255) / 256;

  prep_kernel<<<e8grid, 256, 0, stream>>>(W0, w0t, ei, deg, rank);
  gemm0_kernel<<<(NN + 63) / 64, 256, 0, stream>>>(x, w0t, a_src0, a_dst0, h0b, asrc0, adst0);
  scanA_kernel<<<NB, 256, 0, stream>>>(deg, scanned, bsums);
  scanB_kernel<<<1, 512, 0, stream>>>(bsums, NB);
  scanC_kernel<<<NB, 256, 0, stream>>>(scanned, deg, bsums, rowptr);
  scatter_kernel<<<e8grid, 256, 0, stream>>>(ei, rowptr, rank, csr);
  agg0_kernel<<<NN / 16, 256, 0, stream>>>(csr, rowptr, asrc0, adst0, h0b, b0, agg0b,
                                           bnsumB, bnsqB);
  gemm1_kernel<<<(NN + 63) / 64, 256, 0, stream>>>(agg0b, bnsumB, bnsqB, gamma0, beta0,
                                                   W1, a_src1, a_dst1, h1b, asrc1, adst1);
  agg1_kernel<<<(NN + 3) / 4, 256, 0, stream>>>(csr, rowptr, asrc1, adst1, h1b, b1, out);
}

// Round 13
// 280.526 us; speedup vs baseline: 1.3971x; 1.0760x over previous
//
#include <hip/hip_runtime.h>
#include <hip/hip_bf16.h>
#include <math.h>

#define NN   100000
#define EE   1600000
#define ETOT (NN + EE)
#define IND  128
#define HD   128    // HEADS*HID
#define OD   40
#define NEG  0.2f
#define BNEPS 1e-5f
#define NBKT 16     // BN-stat buckets

#define NGEMM ((NN + 63) / 64)            // 1563 gemm0 tiles
#define NDEG  ((ETOT / 8 + 255) / 256)    // 831 degrank blocks
#define NTRIPLE 831                       // max(ceil(NGEMM/2), NDEG)
#define NFUSED (NTRIPLE * 3)              // 2493

typedef __attribute__((ext_vector_type(8))) short bf16x8;
typedef __attribute__((ext_vector_type(4))) float f32x4;

__device__ __forceinline__ float lrelu(float x) { return x > 0.f ? x : NEG * x; }

__device__ __forceinline__ unsigned pack_bf16(float a, float b) {
  unsigned ua = __float_as_uint(a), ub = __float_as_uint(b);
  ua = (ua + 0x7fffu + ((ua >> 16) & 1u)) >> 16;
  ub = (ub + 0x7fffu + ((ub >> 16) & 1u)) >> 16;
  return ua | (ub << 16);
}
__device__ __forceinline__ float bf16_lo(unsigned v) { return __uint_as_float(v << 16); }
__device__ __forceinline__ float bf16_hi(unsigned v) { return __uint_as_float(v & 0xffff0000u); }

// ---- FUSED: gemm0 (MFMA + alpha logits) blocks interleaved 2:1 with degrank blocks ----
// gemm0 and the CSR degree/rank pass are data-independent; mixing block roles lets
// latency-bound atomic waves hide under MFMA/LDS waves on the same CUs.
__global__ __launch_bounds__(256) void fused0_kernel(const float* __restrict__ x,
                                                     const float* __restrict__ W0,
                                                     const float* __restrict__ a_src0,
                                                     const float* __restrict__ a_dst0,
                                                     unsigned* __restrict__ h0b,
                                                     float* __restrict__ asrc0,
                                                     float* __restrict__ adst0,
                                                     const int* __restrict__ ei,
                                                     int* __restrict__ deg,
                                                     int* __restrict__ rank) {
  __shared__ __align__(16) unsigned As[64][68];   // bf16x2 [row][k/2]
  __shared__ __align__(16) unsigned Wt[128][68];  // bf16x2 [col][k/2]
  int bid = blockIdx.x;
  int trip = bid / 3, rem = bid - trip * 3;
  int t = threadIdx.x;

  if (rem == 2) {
    // ---- degrank role: 8 edges/thread (ETOT, EE multiples of 8) ----
    int i8 = (trip * 256 + t) * 8;
    if (i8 >= ETOT) return;
    int4 dA, dB;
    if (i8 < EE) {
      dA = *(const int4*)&ei[EE + i8];
      dB = *(const int4*)&ei[EE + i8 + 4];
    } else {
      int b = i8 - EE;
      dA = make_int4(b, b + 1, b + 2, b + 3);
      dB = make_int4(b + 4, b + 5, b + 6, b + 7);
    }
    int4 rA, rB;
    rA.x = atomicAdd(&deg[dA.x], 1);
    rA.y = atomicAdd(&deg[dA.y], 1);
    rA.z = atomicAdd(&deg[dA.z], 1);
    rA.w = atomicAdd(&deg[dA.w], 1);
    rB.x = atomicAdd(&deg[dB.x], 1);
    rB.y = atomicAdd(&deg[dB.y], 1);
    rB.z = atomicAdd(&deg[dB.z], 1);
    rB.w = atomicAdd(&deg[dB.w], 1);
    *(int4*)&rank[i8] = rA;
    *(int4*)&rank[i8 + 4] = rB;
    return;
  }

  int gb = trip * 2 + rem;
  if (gb >= NGEMM) return;
  int rowbase = gb * 64;

  // stage W0 transposed+packed directly (coalesced reads along n; W0 is L2-resident)
  for (int idx = t; idx < 128 * 64; idx += 256) {
    int kp = idx >> 7, n = idx & 127;
    float lo = W0[(size_t)(2 * kp) * 128 + n];
    float hi = W0[(size_t)(2 * kp + 1) * 128 + n];
    Wt[n][kp] = pack_bf16(lo, hi);
  }
  for (int idx = t; idx < 64 * 64; idx += 256) {
    int row = idx >> 6, kp = idx & 63;
    int r = rowbase + row;
    int rc = r < NN ? r : NN - 1;
    float2 v = *(const float2*)&x[(size_t)rc * 128 + kp * 2];
    As[row][kp] = pack_bf16(v.x, v.y);
  }
  __syncthreads();

  int lane = t & 63, w = t >> 6;
  int mrow = lane & 15, g = lane >> 4;
  f32x4 acc[8];
#pragma unroll
  for (int nt = 0; nt < 8; nt++) acc[nt] = (f32x4){0.f, 0.f, 0.f, 0.f};
#pragma unroll
  for (int ks = 0; ks < 4; ks++) {
    bf16x8 a = *(const bf16x8*)&As[w * 16 + mrow][ks * 16 + g * 4];
#pragma unroll
    for (int nt = 0; nt < 8; nt++) {
      bf16x8 b = *(const bf16x8*)&Wt[nt * 16 + mrow][ks * 16 + g * 4];
      acc[nt] = __builtin_amdgcn_mfma_f32_16x16x32_bf16(a, b, acc[nt], 0, 0, 0);
    }
  }
  int col = lane & 15;
  float as_[8], ad_[8];
#pragma unroll
  for (int nt = 0; nt < 8; nt++) {
    as_[nt] = a_src0[nt * 16 + col];
    ad_[nt] = a_dst0[nt * 16 + col];
  }
#pragma unroll
  for (int reg = 0; reg < 4; reg++) {
    int r = rowbase + w * 16 + g * 4 + reg;
    bool rok = r < NN;
    float hs0 = acc[0][reg] * as_[0] + acc[1][reg] * as_[1];
    float hs1 = acc[2][reg] * as_[2] + acc[3][reg] * as_[3];
    float hs2 = acc[4][reg] * as_[4] + acc[5][reg] * as_[5];
    float hs3 = acc[6][reg] * as_[6] + acc[7][reg] * as_[7];
    float hd0 = acc[0][reg] * ad_[0] + acc[1][reg] * ad_[1];
    float hd1 = acc[2][reg] * ad_[2] + acc[3][reg] * ad_[3];
    float hd2 = acc[4][reg] * ad_[4] + acc[5][reg] * ad_[5];
    float hd3 = acc[6][reg] * ad_[6] + acc[7][reg] * ad_[7];
#pragma unroll
    for (int mk = 1; mk < 16; mk <<= 1) {
      hs0 += __shfl_xor(hs0, mk); hs1 += __shfl_xor(hs1, mk);
      hs2 += __shfl_xor(hs2, mk); hs3 += __shfl_xor(hs3, mk);
      hd0 += __shfl_xor(hd0, mk); hd1 += __shfl_xor(hd1, mk);
      hd2 += __shfl_xor(hd2, mk); hd3 += __shfl_xor(hd3, mk);
    }
    if ((lane & 15) == 0 && rok) {
      asrc0[r * 4 + 0] = hs0; asrc0[r * 4 + 1] = hs1;
      asrc0[r * 4 + 2] = hs2; asrc0[r * 4 + 3] = hs3;
      adst0[r * 4 + 0] = hd0; adst0[r * 4 + 1] = hd1;
      adst0[r * 4 + 2] = hd2; adst0[r * 4 + 3] = hd3;
    }
#pragma unroll
    for (int nt = 0; nt < 8; nt++) {
      float v = acc[nt][reg];
      float nv = __shfl_xor(v, 1);
      if (!(col & 1) && rok) h0b[(size_t)r * 64 + nt * 8 + (col >> 1)] = pack_bf16(v, nv);
    }
  }
}

// ---------------- CSR scans ----------------
__global__ __launch_bounds__(256) void scanA_kernel(const int* __restrict__ deg,
                                                    int* __restrict__ scanned,
                                                    int* __restrict__ blocksums) {
  __shared__ int s[256];
  int t = threadIdx.x;
  int i = blockIdx.x * 256 + t;
  int v = (i < NN) ? deg[i] : 0;
  s[t] = v;
  __syncthreads();
  for (int off = 1; off < 256; off <<= 1) {
    int add = (t >= off) ? s[t - off] : 0;
    __syncthreads();
    s[t] += add;
    __syncthreads();
  }
  if (i < NN) scanned[i] = s[t];
  if (t == 255) blocksums[blockIdx.x] = s[255];
}

__global__ __launch_bounds__(512) void scanB_kernel(int* __restrict__ blocksums, int NB) {
  __shared__ int s[512];
  int t = threadIdx.x;
  int v = (t < NB) ? blocksums[t] : 0;
  s[t] = v;
  __syncthreads();
  for (int off = 1; off < 512; off <<= 1) {
    int add = (t >= off) ? s[t - off] : 0;
    __syncthreads();
    s[t] += add;
    __syncthreads();
  }
  if (t < NB) blocksums[t] = s[t] - v;  // exclusive block offset
}

__global__ __launch_bounds__(256) void scanC_kernel(const int* __restrict__ scanned,
                                                    const int* __restrict__ deg,
                                                    const int* __restrict__ blocksums,
                                                    int* __restrict__ rowptr) {
  int i = blockIdx.x * 256 + threadIdx.x;
  if (i < NN) rowptr[i] = blocksums[blockIdx.x] + scanned[i] - deg[i];
  if (i == 0) rowptr[NN] = ETOT;
}

// 8 edges/thread scatter
__global__ void scatter_kernel(const int* __restrict__ ei, const int* __restrict__ rowptr,
                               const int* __restrict__ rank, int* __restrict__ csr_src) {
  int i8 = (blockIdx.x * blockDim.x + threadIdx.x) * 8;
  if (i8 >= ETOT) return;
  int4 sA, dA, sB, dB;
  if (i8 < EE) {
    sA = *(const int4*)&ei[i8];
    sB = *(const int4*)&ei[i8 + 4];
    dA = *(const int4*)&ei[EE + i8];
    dB = *(const int4*)&ei[EE + i8 + 4];
  } else {
    int b = i8 - EE;
    sA = make_int4(b, b + 1, b + 2, b + 3);
    sB = make_int4(b + 4, b + 5, b + 6, b + 7);
    dA = sA; dB = sB;
  }
  int4 rA = *(const int4*)&rank[i8];
  int4 rB = *(const int4*)&rank[i8 + 4];
  int p0 = rowptr[dA.x] + rA.x;
  int p1 = rowptr[dA.y] + rA.y;
  int p2 = rowptr[dA.z] + rA.z;
  int p3 = rowptr[dA.w] + rA.w;
  int p4 = rowptr[dB.x] + rB.x;
  int p5 = rowptr[dB.y] + rB.y;
  int p6 = rowptr[dB.z] + rB.z;
  int p7 = rowptr[dB.w] + rB.w;
  csr_src[p0] = sA.x;
  csr_src[p1] = sA.y;
  csr_src[p2] = sA.z;
  csr_src[p3] = sA.w;
  csr_src[p4] = sB.x;
  csr_src[p5] = sB.y;
  csr_src[p6] = sB.z;
  csr_src[p7] = sB.w;
}

// ---- layer-0 aggregate (16 lanes/node, 4-deep) + FUSED BN-stat accumulation ----
// NN is a multiple of 16 -> exactly 6250 full blocks, no early returns.
__global__ __launch_bounds__(256) void agg0_kernel(const int* __restrict__ csr_src,
                                                   const int* __restrict__ rowptr,
                                                   const float* __restrict__ asrc0,
                                                   const float* __restrict__ adst0,
                                                   const unsigned* __restrict__ h0b,
                                                   const float* __restrict__ b0,
                                                   unsigned* __restrict__ agg0b,
                                                   float* __restrict__ bnsumB,
                                                   float* __restrict__ bnsqB) {
  __shared__ float ws[16][4][17];   // [group][head][edge]
  __shared__ int   ss[16][16];
  __shared__ float Lsum[4][16][8], Lsq[4][16][8];
  int t = threadIdx.x;
  int grp = t >> 4;        // node group 0..15
  int p   = t & 15;        // owns channels 8p..8p+7
  int n = blockIdx.x * 16 + grp;
  int start = rowptr[n], end = rowptr[n + 1];
  float4 ad = *(const float4*)&adst0[(size_t)n * 4];
  int head = p >> 2;
  float a0 = 0.f, a1 = 0.f, a2 = 0.f, a3 = 0.f, a4 = 0.f, a5 = 0.f, a6 = 0.f, a7 = 0.f;
  float d0 = 0.f, d1 = 0.f, d2 = 0.f, d3 = 0.f;

  for (int base = start; base < end; base += 16) {
    int cnt = min(16, end - base);
    if (p < cnt) {
      int s = csr_src[base + p];
      float4 as = *(const float4*)&asrc0[(size_t)s * 4];
      float w0 = __expf(lrelu(as.x + ad.x));
      float w1 = __expf(lrelu(as.y + ad.y));
      float w2 = __expf(lrelu(as.z + ad.z));
      float w3 = __expf(lrelu(as.w + ad.w));
      d0 += w0; d1 += w1; d2 += w2; d3 += w3;
      ss[grp][p] = s;
      ws[grp][0][p] = w0;
      ws[grp][1][p] = w1;
      ws[grp][2][p] = w2;
      ws[grp][3][p] = w3;
    }
    __builtin_amdgcn_wave_barrier();
    for (int eb = 0; eb < cnt; eb += 4) {
      int e0 = eb, e1 = eb + 1, e2 = eb + 2, e3 = eb + 3;
      float w0 = ws[grp][head][e0];
      float w1 = (e1 < cnt) ? ws[grp][head][e1] : 0.f;
      float w2 = (e2 < cnt) ? ws[grp][head][e2] : 0.f;
      float w3 = (e3 < cnt) ? ws[grp][head][e3] : 0.f;
      int s0 = ss[grp][e0];
      int s1 = ss[grp][(e1 < cnt) ? e1 : e0];
      int s2 = ss[grp][(e2 < cnt) ? e2 : e0];
      int s3 = ss[grp][(e3 < cnt) ? e3 : e0];
      uint4 h0v = *(const uint4*)&h0b[(size_t)s0 * 64 + p * 4];
      uint4 h1v = *(const uint4*)&h0b[(size_t)s1 * 64 + p * 4];
      uint4 h2v = *(const uint4*)&h0b[(size_t)s2 * 64 + p * 4];
      uint4 h3v = *(const uint4*)&h0b[(size_t)s3 * 64 + p * 4];
      a0 += w0 * bf16_lo(h0v.x); a1 += w0 * bf16_hi(h0v.x);
      a2 += w0 * bf16_lo(h0v.y); a3 += w0 * bf16_hi(h0v.y);
      a4 += w0 * bf16_lo(h0v.z); a5 += w0 * bf16_hi(h0v.z);
      a6 += w0 * bf16_lo(h0v.w); a7 += w0 * bf16_hi(h0v.w);
      a0 += w1 * bf16_lo(h1v.x); a1 += w1 * bf16_hi(h1v.x);
      a2 += w1 * bf16_lo(h1v.y); a3 += w1 * bf16_hi(h1v.y);
      a4 += w1 * bf16_lo(h1v.z); a5 += w1 * bf16_hi(h1v.z);
      a6 += w1 * bf16_lo(h1v.w); a7 += w1 * bf16_hi(h1v.w);
      a0 += w2 * bf16_lo(h2v.x); a1 += w2 * bf16_hi(h2v.x);
      a2 += w2 * bf16_lo(h2v.y); a3 += w2 * bf16_hi(h2v.y);
      a4 += w2 * bf16_lo(h2v.z); a5 += w2 * bf16_hi(h2v.z);
      a6 += w2 * bf16_lo(h2v.w); a7 += w2 * bf16_hi(h2v.w);
      a0 += w3 * bf16_lo(h3v.x); a1 += w3 * bf16_hi(h3v.x);
      a2 += w3 * bf16_lo(h3v.y); a3 += w3 * bf16_hi(h3v.y);
      a4 += w3 * bf16_lo(h3v.z); a5 += w3 * bf16_hi(h3v.z);
      a6 += w3 * bf16_lo(h3v.w); a7 += w3 * bf16_hi(h3v.w);
    }
    __builtin_amdgcn_wave_barrier();
  }
#pragma unroll
  for (int mk = 1; mk < 16; mk <<= 1) {
    d0 += __shfl_xor(d0, mk);
    d1 += __shfl_xor(d1, mk);
    d2 += __shfl_xor(d2, mk);
    d3 += __shfl_xor(d3, mk);
  }
  float dh = head == 0 ? d0 : head == 1 ? d1 : head == 2 ? d2 : d3;
  float rd = 1.f / dh;
  int c = p * 8;
  float4 b1v = *(const float4*)&b0[c];
  float4 b2v = *(const float4*)&b0[c + 4];
  float o0 = a0 * rd + b1v.x, o1 = a1 * rd + b1v.y;
  float o2 = a2 * rd + b1v.z, o3 = a3 * rd + b1v.w;
  float o4 = a4 * rd + b2v.x, o5 = a5 * rd + b2v.y;
  float o6 = a6 * rd + b2v.z, o7 = a7 * rd + b2v.w;
  uint4 o;
  o.x = pack_bf16(o0, o1);
  o.y = pack_bf16(o2, o3);
  o.z = pack_bf16(o4, o5);
  o.w = pack_bf16(o6, o7);
  *(uint4*)&agg0b[(size_t)n * 64 + p * 4] = o;

  // fused BN stats: reduce the 4 groups within this wave, then LDS, then bucketed atomics
  float s0 = o0, s1 = o1, s2 = o2, s3 = o3, s4 = o4, s5 = o5, s6 = o6, s7 = o7;
  float q0 = o0 * o0, q1 = o1 * o1, q2 = o2 * o2, q3 = o3 * o3;
  float q4 = o4 * o4, q5 = o5 * o5, q6 = o6 * o6, q7 = o7 * o7;
#pragma unroll
  for (int mk = 16; mk < 64; mk <<= 1) {
    s0 += __shfl_xor(s0, mk); s1 += __shfl_xor(s1, mk);
    s2 += __shfl_xor(s2, mk); s3 += __shfl_xor(s3, mk);
    s4 += __shfl_xor(s4, mk); s5 += __shfl_xor(s5, mk);
    s6 += __shfl_xor(s6, mk); s7 += __shfl_xor(s7, mk);
    q0 += __shfl_xor(q0, mk); q1 += __shfl_xor(q1, mk);
    q2 += __shfl_xor(q2, mk); q3 += __shfl_xor(q3, mk);
    q4 += __shfl_xor(q4, mk); q5 += __shfl_xor(q5, mk);
    q6 += __shfl_xor(q6, mk); q7 += __shfl_xor(q7, mk);
  }
  int lane = t & 63, wv = t >> 6;
  if (lane < 16) {
    Lsum[wv][lane][0] = s0; Lsum[wv][lane][1] = s1;
    Lsum[wv][lane][2] = s2; Lsum[wv][lane][3] = s3;
    Lsum[wv][lane][4] = s4; Lsum[wv][lane][5] = s5;
    Lsum[wv][lane][6] = s6; Lsum[wv][lane][7] = s7;
    Lsq[wv][lane][0] = q0; Lsq[wv][lane][1] = q1;
    Lsq[wv][lane][2] = q2; Lsq[wv][lane][3] = q3;
    Lsq[wv][lane][4] = q4; Lsq[wv][lane][5] = q5;
    Lsq[wv][lane][6] = q6; Lsq[wv][lane][7] = q7;
  }
  __syncthreads();
  if (t < 128) {
    int pp = t >> 3, jj = t & 7;
    float s = Lsum[0][pp][jj] + Lsum[1][pp][jj] + Lsum[2][pp][jj] + Lsum[3][pp][jj];
    float q = Lsq[0][pp][jj] + Lsq[1][pp][jj] + Lsq[2][pp][jj] + Lsq[3][pp][jj];
    int bkt = blockIdx.x & (NBKT - 1);
    atomicAdd(&bnsumB[bkt * 128 + t], s);
    atomicAdd(&bnsqB[bkt * 128 + t], q);
  }
}

// ---- GEMM1 via MFMA: BN finalize in prologue, fused BN+ELU, alpha1, bf16 h1 ----
__global__ __launch_bounds__(256) void gemm1_kernel(const unsigned* __restrict__ agg0b,
                                                    const float* __restrict__ bnsumB,
                                                    const float* __restrict__ bnsqB,
                                                    const float* __restrict__ gamma,
                                                    const float* __restrict__ beta,
                                                    const float* __restrict__ W1,
                                                    const float* __restrict__ a_src1,
                                                    const float* __restrict__ a_dst1,
                                                    unsigned* __restrict__ h1b,
                                                    float* __restrict__ asrc1,
                                                    float* __restrict__ adst1) {
  __shared__ __align__(16) unsigned As[64][68];
  __shared__ __align__(16) unsigned Wt[48][68];
  __shared__ float bnsc[128], bnsh[128];
  int t = threadIdx.x;
  int rowbase = blockIdx.x * 64;

  if (t < 128) {
    float s = 0.f, q = 0.f;
#pragma unroll
    for (int k = 0; k < NBKT; k++) {
      s += bnsumB[k * 128 + t];
      q += bnsqB[k * 128 + t];
    }
    float mu = s / (float)NN;
    float var = q / (float)NN - mu * mu;
    float sc = gamma[t] / sqrtf(var + BNEPS);
    bnsc[t] = sc;
    bnsh[t] = beta[t] - mu * sc;
  }
  for (int idx = t; idx < 48 * 64; idx += 256) {
    int c = idx >> 6, kp = idx & 63;
    float lo = (c < OD) ? W1[(size_t)(2 * kp) * OD + c] : 0.f;
    float hi = (c < OD) ? W1[(size_t)(2 * kp + 1) * OD + c] : 0.f;
    Wt[c][kp] = pack_bf16(lo, hi);
  }
  __syncthreads();
  for (int idx = t; idx < 64 * 16; idx += 256) {
    int row = idx >> 4, c4 = idx & 15;
    int r = rowbase + row;
    int rc = r < NN ? r : NN - 1;
    int k = c4 * 8;
    uint4 hv = *(const uint4*)&agg0b[(size_t)rc * 64 + c4 * 4];
    float y0 = bf16_lo(hv.x) * bnsc[k + 0] + bnsh[k + 0];
    float y1 = bf16_hi(hv.x) * bnsc[k + 1] + bnsh[k + 1];
    float y2 = bf16_lo(hv.y) * bnsc[k + 2] + bnsh[k + 2];
    float y3 = bf16_hi(hv.y) * bnsc[k + 3] + bnsh[k + 3];
    float y4 = bf16_lo(hv.z) * bnsc[k + 4] + bnsh[k + 4];
    float y5 = bf16_hi(hv.z) * bnsc[k + 5] + bnsh[k + 5];
    float y6 = bf16_lo(hv.w) * bnsc[k + 6] + bnsh[k + 6];
    float y7 = bf16_hi(hv.w) * bnsc[k + 7] + bnsh[k + 7];
    y0 = y0 > 0.f ? y0 : expm1f(y0);
    y1 = y1 > 0.f ? y1 : expm1f(y1);
    y2 = y2 > 0.f ? y2 : expm1f(y2);
    y3 = y3 > 0.f ? y3 : expm1f(y3);
    y4 = y4 > 0.f ? y4 : expm1f(y4);
    y5 = y5 > 0.f ? y5 : expm1f(y5);
    y6 = y6 > 0.f ? y6 : expm1f(y6);
    y7 = y7 > 0.f ? y7 : expm1f(y7);
    As[row][c4 * 4 + 0] = pack_bf16(y0, y1);
    As[row][c4 * 4 + 1] = pack_bf16(y2, y3);
    As[row][c4 * 4 + 2] = pack_bf16(y4, y5);
    As[row][c4 * 4 + 3] = pack_bf16(y6, y7);
  }
  __syncthreads();

  int lane = t & 63, w = t >> 6;
  int mrow = lane & 15, g = lane >> 4;
  f32x4 acc0 = {0.f, 0.f, 0.f, 0.f};
  f32x4 acc1 = {0.f, 0.f, 0.f, 0.f};
  f32x4 acc2 = {0.f, 0.f, 0.f, 0.f};
#pragma unroll
  for (int ks = 0; ks < 4; ks++) {
    bf16x8 a = *(const bf16x8*)&As[w * 16 + mrow][ks * 16 + g * 4];
    bf16x8 b0v = *(const bf16x8*)&Wt[mrow][ks * 16 + g * 4];
    bf16x8 b1v = *(const bf16x8*)&Wt[16 + mrow][ks * 16 + g * 4];
    bf16x8 b2v = *(const bf16x8*)&Wt[32 + mrow][ks * 16 + g * 4];
    acc0 = __builtin_amdgcn_mfma_f32_16x16x32_bf16(a, b0v, acc0, 0, 0, 0);
    acc1 = __builtin_amdgcn_mfma_f32_16x16x32_bf16(a, b1v, acc1, 0, 0, 0);
    acc2 = __builtin_amdgcn_mfma_f32_16x16x32_bf16(a, b2v, acc2, 0, 0, 0);
  }
  int col = lane & 15;
  float as0 = (col < OD)      ? a_src1[col]      : 0.f;
  float as1 = (16 + col < OD) ? a_src1[16 + col] : 0.f;
  float as2 = (32 + col < OD) ? a_src1[32 + col] : 0.f;
  float ad0 = (col < OD)      ? a_dst1[col]      : 0.f;
  float ad1 = (16 + col < OD) ? a_dst1[16 + col] : 0.f;
  float ad2 = (32 + col < OD) ? a_dst1[32 + col] : 0.f;
#pragma unroll
  for (int reg = 0; reg < 4; reg++) {
    int r = rowbase + w * 16 + g * 4 + reg;
    float v0 = acc0[reg], v1 = acc1[reg], v2 = acc2[reg];
    float ps = v0 * as0 + v1 * as1 + v2 * as2;
    float pd = v0 * ad0 + v1 * ad1 + v2 * ad2;
#pragma unroll
    for (int mk = 1; mk < 16; mk <<= 1) { ps += __shfl_xor(ps, mk); pd += __shfl_xor(pd, mk); }
    bool rok = r < NN;
    if ((lane & 15) == 0 && rok) { asrc1[r] = ps; adst1[r] = pd; }
    float n0 = __shfl_xor(v0, 1), n1 = __shfl_xor(v1, 1), n2 = __shfl_xor(v2, 1);
    if (!(col & 1) && rok) {
      h1b[(size_t)r * 20 + ((col) >> 1)]      = pack_bf16(v0, n0);
      h1b[(size_t)r * 20 + ((16 + col) >> 1)] = pack_bf16(v1, n1);
      if (32 + col < OD) h1b[(size_t)r * 20 + ((32 + col) >> 1)] = pack_bf16(v2, n2);
    }
  }
}

// ---- layer-1 aggregate: one wave/node; 6 edges x 10 lanes, uint2 loads ----
__global__ __launch_bounds__(256) void agg1_kernel(const int* __restrict__ csr_src,
                                                   const int* __restrict__ rowptr,
                                                   const float* __restrict__ asrc1,
                                                   const float* __restrict__ adst1,
                                                   const unsigned* __restrict__ h1b,
                                                   const float* __restrict__ b1,
                                                   float* __restrict__ out) {
  __shared__ float ws[4][64];
  __shared__ int   ss[4][64];
  int t = threadIdx.x;
  int lane = t & 63, wv = t >> 6;
  int n = blockIdx.x * 4 + wv;
  if (n >= NN) return;
  int start = rowptr[n], end = rowptr[n + 1];
  float ad = adst1[n];
  int esub = lane / 10;          // 0..5 for lanes 0..59
  int c2   = lane - esub * 10;   // u32-pair index; channels 4*c2..4*c2+3
  float dsum = 0.f;
  float acc0 = 0.f, acc1 = 0.f, acc2 = 0.f, acc3 = 0.f;
  for (int base = start; base < end; base += 64) {
    int cnt = min(64, end - base);
    if (lane < cnt) {
      int s = csr_src[base + lane];
      float w = __expf(lrelu(asrc1[s] + ad));
      dsum += w;
      ss[wv][lane] = s;
      ws[wv][lane] = w;
    }
    __builtin_amdgcn_wave_barrier();
    if (lane < 60) {
      int e = esub;
      for (; e + 18 < cnt; e += 24) {
        int s0 = ss[wv][e], s1 = ss[wv][e + 6], s2 = ss[wv][e + 12], s3 = ss[wv][e + 18];
        uint2 u0 = *(const uint2*)&h1b[(size_t)s0 * 20 + c2 * 2];
        uint2 u1 = *(const uint2*)&h1b[(size_t)s1 * 20 + c2 * 2];
        uint2 u2 = *(const uint2*)&h1b[(size_t)s2 * 20 + c2 * 2];
        uint2 u3 = *(const uint2*)&h1b[(size_t)s3 * 20 + c2 * 2];
        float w0 = ws[wv][e], w1 = ws[wv][e + 6], w2 = ws[wv][e + 12], w3 = ws[wv][e + 18];
        acc0 += w0 * bf16_lo(u0.x); acc1 += w0 * bf16_hi(u0.x);
        acc2 += w0 * bf16_lo(u0.y); acc3 += w0 * bf16_hi(u0.y);
        acc0 += w1 * bf16_lo(u1.x); acc1 += w1 * bf16_hi(u1.x);
        acc2 += w1 * bf16_lo(u1.y); acc3 += w1 * bf16_hi(u1.y);
        acc0 += w2 * bf16_lo(u2.x); acc1 += w2 * bf16_hi(u2.x);
        acc2 += w2 * bf16_lo(u2.y); acc3 += w2 * bf16_hi(u2.y);
        acc0 += w3 * bf16_lo(u3.x); acc1 += w3 * bf16_hi(u3.x);
        acc2 += w3 * bf16_lo(u3.y); acc3 += w3 * bf16_hi(u3.y);
      }
      for (; e < cnt; e += 6) {
        int s = ss[wv][e];
        float w = ws[wv][e];
        uint2 u = *(const uint2*)&h1b[(size_t)s * 20 + c2 * 2];
        acc0 += w * bf16_lo(u.x); acc1 += w * bf16_hi(u.x);
        acc2 += w * bf16_lo(u.y); acc3 += w * bf16_hi(u.y);
      }
    }
    __builtin_amdgcn_wave_barrier();
  }
#pragma unroll
  for (int mk = 1; mk < 64; mk <<= 1) dsum += __shfl_xor(dsum, mk);
  float rd = 1.f / dsum;
  // combine the 6 esub groups down to lanes 0..9 (read ALL partials before summing)
  float p01 = __shfl(acc0, lane + 10), p02 = __shfl(acc0, lane + 20);
  float p03 = __shfl(acc0, lane + 30), p04 = __shfl(acc0, lane + 40);
  float p05 = __shfl(acc0, lane + 50);
  float p11 = __shfl(acc1, lane + 10), p12 = __shfl(acc1, lane + 20);
  float p13 = __shfl(acc1, lane + 30), p14 = __shfl(acc1, lane + 40);
  float p15 = __shfl(acc1, lane + 50);
  float p21 = __shfl(acc2, lane + 10), p22 = __shfl(acc2, lane + 20);
  float p23 = __shfl(acc2, lane + 30), p24 = __shfl(acc2, lane + 40);
  float p25 = __shfl(acc2, lane + 50);
  float p31 = __shfl(acc3, lane + 10), p32 = __shfl(acc3, lane + 20);
  float p33 = __shfl(acc3, lane + 30), p34 = __shfl(acc3, lane + 40);
  float p35 = __shfl(acc3, lane + 50);
  if (lane < 10) {
    float t0 = acc0 + p01 + p02 + p03 + p04 + p05;
    float t1 = acc1 + p11 + p12 + p13 + p14 + p15;
    float t2 = acc2 + p21 + p22 + p23 + p24 + p25;
    float t3 = acc3 + p31 + p32 + p33 + p34 + p35;
    float4 bv = *(const float4*)&b1[lane * 4];
    float4 o;
    o.x = t0 * rd + bv.x;
    o.y = t1 * rd + bv.y;
    o.z = t2 * rd + bv.z;
    o.w = t3 * rd + bv.w;
    *(float4*)&out[(size_t)n * 40 + lane * 4] = o;
  }
}

// ---------------- host launch ----------------
extern "C" void kernel_launch(void* const* d_in, const int* in_sizes, int n_in,
                              void* d_out, int out_size, void* d_ws, size_t ws_size,
                              hipStream_t stream) {
  const float* x       = (const float*)d_in[0];
  const int*   ei      = (const int*)d_in[1];
  const float* W0      = (const float*)d_in[2];
  const float* a_src0  = (const float*)d_in[3];
  const float* a_dst0  = (const float*)d_in[4];
  const float* b0      = (const float*)d_in[5];
  const float* gamma0  = (const float*)d_in[6];
  const float* beta0   = (const float*)d_in[7];
  const float* W1      = (const float*)d_in[8];
  const float* a_src1  = (const float*)d_in[9];
  const float* a_dst1  = (const float*)d_in[10];
  const float* b1      = (const float*)d_in[11];
  float* out = (float*)d_out;

  char* ws = (char*)d_ws;
  size_t off = 0;
  auto alloc = [&](size_t bytes) {
    void* p = ws + off;
    off += (bytes + 255) & ~(size_t)255;
    return p;
  };
  // zero-region first: deg, bnsumB, bnsqB (contiguous)
  int*   deg      = (int*)alloc((size_t)NN * 4);
  float* bnsumB   = (float*)alloc(NBKT * 128 * 4);
  float* bnsqB    = (float*)alloc(NBKT * 128 * 4);
  unsigned* h0b   = (unsigned*)alloc((size_t)NN * 64 * 4);   // bf16x2
  unsigned* agg0b = (unsigned*)alloc((size_t)NN * 64 * 4);   // bf16x2
  unsigned* h1b   = (unsigned*)alloc((size_t)NN * 20 * 4);   // bf16x2
  float* asrc0    = (float*)alloc((size_t)NN * 4 * 4);
  float* adst0    = (float*)alloc((size_t)NN * 4 * 4);
  float* asrc1    = (float*)alloc((size_t)NN * 4);
  float* adst1    = (float*)alloc((size_t)NN * 4);
  int*   rowptr   = (int*)alloc((size_t)(NN + 1) * 4);
  int*   scanned  = (int*)alloc((size_t)NN * 4);
  int*   csr      = (int*)alloc((size_t)ETOT * 4);
  int*   rank     = (int*)alloc((size_t)ETOT * 4);
  int*   bsums    = (int*)alloc(512 * 4);
  (void)ws_size; (void)in_sizes; (void)n_in; (void)out_size;

  size_t zbytes = (char*)(bnsqB + NBKT * 128) - (char*)deg;
  hipMemsetAsync(deg, 0, zbytes, stream);

  const int NB = (NN + 255) / 256;
  const int e8grid = (ETOT / 8 + 255) / 256;

  fused0_kernel<<<NFUSED, 256, 0, stream>>>(x, W0, a_src0, a_dst0, h0b, asrc0, adst0,
                                            ei, deg, rank);
  scanA_kernel<<<NB, 256, 0, stream>>>(deg, scanned, bsums);
  scanB_kernel<<<1, 512, 0, stream>>>(bsums, NB);
  scanC_kernel<<<NB, 256, 0, stream>>>(scanned, deg, bsums, rowptr);
  scatter_kernel<<<e8grid, 256, 0, stream>>>(ei, rowptr, rank, csr);
  agg0_kernel<<<NN / 16, 256, 0, stream>>>(csr, rowptr, asrc0, adst0, h0b, b0, agg0b,
                                           bnsumB, bnsqB);
  gemm1_kernel<<<(NN + 63) / 64, 256, 0, stream>>>(agg0b, bnsumB, bnsqB, gamma0, beta0,
                                                   W1, a_src1, a_dst1, h1b, asrc1, adst1);
  agg1_kernel<<<(NN + 3) / 4, 256, 0, stream>>>(csr, rowptr, asrc1, adst1, h1b, b1, out);
}